// Round 3
// baseline (2428.009 us; speedup 1.0000x reference)
//
#include <hip/hip_runtime.h>

typedef unsigned short bf16;
typedef __attribute__((ext_vector_type(8))) short bf16x8;
typedef __attribute__((ext_vector_type(4))) float f32x4;
typedef unsigned short u16x4 __attribute__((ext_vector_type(4)));

#define DEVFN static __device__ __forceinline__

#define NL 12

DEVFN unsigned short f2bf(float f) {
  union { float f; unsigned u; } v; v.f = f;
  unsigned u = v.u;
  unsigned r = (u + 0x7fffu + ((u >> 16) & 1u)) >> 16;  // RNE
  return (unsigned short)r;
}
DEVFN float bf2f(unsigned short h) {
  union { unsigned u; float f; } v; v.u = ((unsigned)h) << 16; return v.f;
}

#define MFMA_BF16(a, b, c) __builtin_amdgcn_mfma_f32_16x16x32_bf16((a), (b), (c), 0, 0, 0)

// ---------------------------------------------------------------------------
// Weight prep: hi/lo bf16 split of every weight. Per-layer bf16 block (1310720):
//   [0,196608)         Wqkv hi (rows head-major permuted for q,k,v)
//   [196608,393216)    Wqkv lo
//   [393216,458752)    Wm hi (cols permuted)
//   [458752,524288)    Wm lo
//   [524288,786432)    W1 hi
//   [786432,1048576)   W1 lo
//   [1048576,1179648)  W2 hi
//   [1179648,1310720)  W2 lo
// Per-layer f32 bias block (2304): bqkv[768] | bm[256] | geff[512] | beff[512] | b2[256]
// ---------------------------------------------------------------------------
__global__ void prep_weights(const float* __restrict__ Wq, const float* __restrict__ bq,
                             const float* __restrict__ Wk, const float* __restrict__ bk,
                             const float* __restrict__ Wv, const float* __restrict__ bv,
                             const float* __restrict__ Wm, const float* __restrict__ bm,
                             const float* __restrict__ W1, const float* __restrict__ b1,
                             const float* __restrict__ gm, const float* __restrict__ bt,
                             const float* __restrict__ W2, const float* __restrict__ b2,
                             bf16* __restrict__ Wbf, float* __restrict__ bias)
{
  int l = blockIdx.y;
  bf16* wl = Wbf + (size_t)l * 1310720;
  float* bl = bias + l * 2304;
  int idx = blockIdx.x * blockDim.x + threadIdx.x;
  if (idx >= 1310720 + 2304) return;
  const float INV = 1.0f / sqrtf(1.0f + 1e-5f);

  float w = 0.f;
  int lo = 0;
  if (idx < 393216) {                         // Wqkv
    int j = idx; lo = (j >= 196608); j -= lo * 196608;
    int t = j >> 16;
    int p = (j >> 8) & 255;
    int k = j & 255;
    int c = ((p & 63) << 2) | (p >> 6);       // p = h*64+i -> c = i*4+h
    const float* W = (t == 0) ? Wq : (t == 1) ? Wk : Wv;
    w = W[(size_t)l * 65536 + c * 256 + k];
  } else if (idx < 524288) {                  // Wm (cols permuted)
    int j = idx - 393216; lo = (j >= 65536); j -= lo * 65536;
    int o = j >> 8, p = j & 255;
    int c = ((p & 63) << 2) | (p >> 6);
    w = Wm[(size_t)l * 65536 + o * 256 + c];
  } else if (idx < 1048576) {                 // W1
    int j = idx - 524288; lo = (j >= 262144); j &= 262143;
    w = W1[(size_t)l * 262144 + j];
  } else if (idx < 1310720) {                 // W2
    int j = idx - 1048576; lo = (j >= 131072); j &= 131071;
    w = W2[(size_t)l * 131072 + j];
  } else {
    int j = idx - 1310720;
    if (j < 768) {
      int t = j >> 8, p = j & 255;
      int c = ((p & 63) << 2) | (p >> 6);
      const float* bsrc = (t == 0) ? bq : (t == 1) ? bk : bv;
      bl[j] = bsrc[l * 256 + c];
    } else if (j < 1024) {
      bl[j] = bm[l * 256 + (j - 768)];
    } else if (j < 1536) {
      bl[j] = gm[l * 512 + (j - 1024)] * INV;
    } else if (j < 2048) {
      int o = j - 1536;
      bl[j] = gm[l * 512 + o] * INV * b1[l * 512 + o] + bt[l * 512 + o];
    } else {
      bl[j] = b2[l * 256 + (j - 2048)];
    }
    return;
  }
  unsigned short hi = f2bf(w);
  wl[idx] = lo ? f2bf(w - bf2f(hi)) : hi;
}

// ---------------------------------------------------------------------------
// Input transpose: desc [b,d,n] fp32 -> Dm [xi,256] fp32; Hin[:,0:256]=x hi;
// XMl[:,0:256]=x lo (both lda 512).
// ---------------------------------------------------------------------------
__global__ void transpose_in(const float* __restrict__ s0, const float* __restrict__ s1,
                             float* __restrict__ Dm, bf16* __restrict__ Hin,
                             bf16* __restrict__ XMl)
{
  __shared__ float t[32][33];
  int db = blockIdx.z;
  int dsc = db >> 1, bi = db & 1;
  const float* src = dsc ? s1 : s0;
  int n0 = blockIdx.x * 32, d0 = blockIdx.y * 32;
  int tx = threadIdx.x, ty = threadIdx.y;
  #pragma unroll
  for (int i = 0; i < 32; i += 8)
    t[ty + i][tx] = src[(size_t)(bi * 256 + d0 + ty + i) * 2048 + n0 + tx];
  __syncthreads();
  #pragma unroll
  for (int i = 0; i < 32; i += 8) {
    size_t xi = (size_t)db * 2048 + n0 + ty + i;
    float v = t[tx][ty + i];
    Dm[xi * 256 + d0 + tx] = v;
    unsigned short hi = f2bf(v);
    Hin[xi * 512 + d0 + tx] = hi;
    XMl[xi * 512 + d0 + tx] = f2bf(v - bf2f(hi));
  }
}

__global__ void transpose_out(const float* __restrict__ Dm, float* __restrict__ out)
{
  __shared__ float t[32][33];
  int db = blockIdx.z;
  int n0 = blockIdx.x * 32, d0 = blockIdx.y * 32;
  int tx = threadIdx.x, ty = threadIdx.y;
  #pragma unroll
  for (int i = 0; i < 32; i += 8)
    t[ty + i][tx] = Dm[((size_t)db * 2048 + n0 + ty + i) * 256 + d0 + tx];
  __syncthreads();
  #pragma unroll
  for (int i = 0; i < 32; i += 8)
    out[(size_t)(db * 256 + d0 + ty + i) * 2048 + n0 + tx] = t[tx][ty + i];
}

// ---------------------------------------------------------------------------
// 3-term split GEMM: C = Ah·Wh^T + Al·Wh^T + Ah·Wl^T  (~fp32 accuracy)
// Tile 128x128, BK=32, 4 waves. Granule-XOR-swizzled LDS (64B rows).
// EPI 0: Q/K  -> hi/lo (o0..o3 = Qh,Ql,Kh,Kl), +bias
// EPI 1: V    -> Vt hi/lo transposed [db,256,2048], +bias
// EPI 2: merge-> Hin[:,256:512] hi, XMl[:,256:512] lo, +bias
// EPI 3: MLP1 -> BN+ReLU, Hbh/Hbl [xi,512]
// EPI 4: MLP2 -> Dm += acc+b2 (fp32); Hin[:,0:256] hi, XMl[:,0:256] lo
// ---------------------------------------------------------------------------
DEVFN int gsw(int row, int col) { return row * 32 + (col ^ ((row & 3) << 3)); }

template<int EPI>
__global__ __launch_bounds__(256) void gemm3(
    const bf16* __restrict__ Ah, int lda,
    const bf16* __restrict__ Al, int ldal,
    const bf16* __restrict__ Wh, const bf16* __restrict__ Wl, int K,
    const float* __restrict__ b0, const float* __restrict__ b1,
    bf16* __restrict__ o0, bf16* __restrict__ o1,
    bf16* __restrict__ o2, bf16* __restrict__ o3,
    float* __restrict__ of)
{
  __shared__ bf16 AsH[128 * 32];
  __shared__ bf16 AsL[128 * 32];
  __shared__ bf16 BsH[128 * 32];
  __shared__ bf16 BsL[128 * 32];
  int tid = threadIdx.x, lane = tid & 63, wid = tid >> 6;
  int wr = wid >> 1, wc = wid & 1;
  int m0 = blockIdx.x * 128, n0 = blockIdx.y * 128;
  int r0 = tid >> 2, kc0 = (tid & 3) << 3;
  const bf16* Aph = Ah + (size_t)(m0 + r0) * lda + kc0;
  const bf16* Apl = Al + (size_t)(m0 + r0) * ldal + kc0;
  const bf16* Wph = Wh + (size_t)(n0 + r0) * K + kc0;
  const bf16* Wpl = Wl + (size_t)(n0 + r0) * K + kc0;
  size_t ah_s = (size_t)64 * lda, al_s = (size_t)64 * ldal, w_s = (size_t)64 * K;

  f32x4 zero = {0.f, 0.f, 0.f, 0.f};
  f32x4 acc[4][4];
  #pragma unroll
  for (int i = 0; i < 4; i++)
    #pragma unroll
    for (int j = 0; j < 4; j++) acc[i][j] = zero;

  int4 ah0 = *(const int4*)Aph, ah1 = *(const int4*)(Aph + ah_s);
  int4 al0 = *(const int4*)Apl, al1 = *(const int4*)(Apl + al_s);
  int4 bh0 = *(const int4*)Wph, bh1 = *(const int4*)(Wph + w_s);
  int4 bl0 = *(const int4*)Wpl, bl1 = *(const int4*)(Wpl + w_s);

  int fr = lane & 15, kof = (lane >> 4) << 3;
  for (int k0 = 0; k0 < K; k0 += 32) {
    __syncthreads();
    *(int4*)(&AsH[gsw(r0, kc0)]) = ah0;
    *(int4*)(&AsH[gsw(64 + r0, kc0)]) = ah1;
    *(int4*)(&AsL[gsw(r0, kc0)]) = al0;
    *(int4*)(&AsL[gsw(64 + r0, kc0)]) = al1;
    *(int4*)(&BsH[gsw(r0, kc0)]) = bh0;
    *(int4*)(&BsH[gsw(64 + r0, kc0)]) = bh1;
    *(int4*)(&BsL[gsw(r0, kc0)]) = bl0;
    *(int4*)(&BsL[gsw(64 + r0, kc0)]) = bl1;
    if (k0 + 32 < K) {
      ah0 = *(const int4*)(Aph + k0 + 32);
      ah1 = *(const int4*)(Aph + k0 + 32 + ah_s);
      al0 = *(const int4*)(Apl + k0 + 32);
      al1 = *(const int4*)(Apl + k0 + 32 + al_s);
      bh0 = *(const int4*)(Wph + k0 + 32);
      bh1 = *(const int4*)(Wph + k0 + 32 + w_s);
      bl0 = *(const int4*)(Wpl + k0 + 32);
      bl1 = *(const int4*)(Wpl + k0 + 32 + w_s);
    }
    __syncthreads();
    bf16x8 afh[4], afl[4], bfh[4], bfl[4];
    #pragma unroll
    for (int i = 0; i < 4; i++) {
      afh[i] = *(const bf16x8*)(&AsH[gsw(wr * 64 + i * 16 + fr, kof)]);
      afl[i] = *(const bf16x8*)(&AsL[gsw(wr * 64 + i * 16 + fr, kof)]);
      bfh[i] = *(const bf16x8*)(&BsH[gsw(wc * 64 + i * 16 + fr, kof)]);
      bfl[i] = *(const bf16x8*)(&BsL[gsw(wc * 64 + i * 16 + fr, kof)]);
    }
    #pragma unroll
    for (int mi = 0; mi < 4; mi++)
      #pragma unroll
      for (int ni = 0; ni < 4; ni++) {
        acc[mi][ni] = MFMA_BF16(afh[mi], bfh[ni], acc[mi][ni]);
        acc[mi][ni] = MFMA_BF16(afl[mi], bfh[ni], acc[mi][ni]);
        acc[mi][ni] = MFMA_BF16(afh[mi], bfl[ni], acc[mi][ni]);
      }
  }

  #pragma unroll
  for (int mi = 0; mi < 4; mi++) {
    #pragma unroll
    for (int ni = 0; ni < 4; ni++) {
      int mrow = m0 + wr * 64 + mi * 16 + ((lane >> 4) << 2);
      int ocol = n0 + wc * 64 + ni * 16 + fr;
      if constexpr (EPI == 0) {          // Q/K hi+lo
        float bb = b0[ocol];
        bf16* Dh = (ocol < 256) ? o0 : o2;
        bf16* Dl = (ocol < 256) ? o1 : o3;
        int oo = ocol & 255;
        #pragma unroll
        for (int r = 0; r < 4; r++) {
          float v = acc[mi][ni][r] + bb;
          unsigned short hi = f2bf(v);
          Dh[(size_t)(mrow + r) * 256 + oo] = hi;
          Dl[(size_t)(mrow + r) * 256 + oo] = f2bf(v - bf2f(hi));
        }
      } else if constexpr (EPI == 1) {   // V transposed hi+lo
        float bb = b0[ocol];
        int dbi = mrow >> 11, nn = mrow & 2047;
        u16x4 ph, pl;
        #pragma unroll
        for (int r = 0; r < 4; r++) {
          float v = acc[mi][ni][r] + bb;
          unsigned short hi = f2bf(v);
          ph[r] = hi;
          pl[r] = f2bf(v - bf2f(hi));
        }
        *(u16x4*)(&o0[((size_t)dbi * 256 + ocol) * 2048 + nn]) = ph;
        *(u16x4*)(&o1[((size_t)dbi * 256 + ocol) * 2048 + nn]) = pl;
      } else if constexpr (EPI == 2) {   // merge -> msg hi+lo
        float bb = b0[ocol];
        #pragma unroll
        for (int r = 0; r < 4; r++) {
          float v = acc[mi][ni][r] + bb;
          unsigned short hi = f2bf(v);
          o0[(size_t)(mrow + r) * 512 + 256 + ocol] = hi;
          o1[(size_t)(mrow + r) * 512 + 256 + ocol] = f2bf(v - bf2f(hi));
        }
      } else if constexpr (EPI == 3) {   // BN+ReLU hi+lo
        float ge = b0[ocol], be = b1[ocol];
        #pragma unroll
        for (int r = 0; r < 4; r++) {
          float v = fmaxf(ge * acc[mi][ni][r] + be, 0.f);
          unsigned short hi = f2bf(v);
          o0[(size_t)(mrow + r) * 512 + ocol] = hi;
          o1[(size_t)(mrow + r) * 512 + ocol] = f2bf(v - bf2f(hi));
        }
      } else {                           // EPI 4: residual
        float bb = b0[ocol];
        #pragma unroll
        for (int r = 0; r < 4; r++) {
          size_t ix = (size_t)(mrow + r) * 256 + ocol;
          float d = of[ix] + acc[mi][ni][r] + bb;
          of[ix] = d;
          unsigned short hi = f2bf(d);
          o0[(size_t)(mrow + r) * 512 + ocol] = hi;
          o1[(size_t)(mrow + r) * 512 + ocol] = f2bf(d - bf2f(hi));
        }
      }
    }
  }
}

// ---------------------------------------------------------------------------
// Flash attention, full split precision: 3-term QK^T and 3-term PV.
// Grid (16 n-blocks, 16 inst), 512 threads. QB=128, KB=64, dh=64.
// ---------------------------------------------------------------------------
DEVFN int swz(int row, int col) { return row * 64 + (col ^ ((row & 7) << 3)); }

__global__ __launch_bounds__(512) void attn3(
    const bf16* __restrict__ Qh, const bf16* __restrict__ Ql,
    const bf16* __restrict__ Kh, const bf16* __restrict__ Kl,
    const bf16* __restrict__ Vth, const bf16* __restrict__ Vtl,
    bf16* __restrict__ Oh, bf16* __restrict__ Ol, int cross)
{
  __shared__ bf16 Qsh[128 * 64];
  __shared__ bf16 Qsl[128 * 64];
  __shared__ bf16 Ksh[64 * 64];
  __shared__ bf16 Ksl[64 * 64];
  __shared__ bf16 Vsh[64 * 64];
  __shared__ bf16 Vsl[64 * 64];
  __shared__ bf16 Psh[8 * 16 * 64];
  __shared__ bf16 Psl[8 * 16 * 64];
  int tid = threadIdx.x, lane = tid & 63, w = tid >> 6;
  int inst = blockIdx.y;
  int db = inst >> 2, hd = inst & 3;
  int dsc = db >> 1, bi = db & 1;
  int sdb = (cross ? (1 - dsc) : dsc) * 2 + bi;
  size_t xq = (size_t)db * 2048;
  size_t xs = (size_t)sdb * 2048;
  int n0 = blockIdx.x * 128;

  for (int c = tid; c < 1024; c += 512) {
    int row = c >> 3, kc = (c & 7) << 3;
    size_t g = (xq + n0 + row) * 256 + hd * 64 + kc;
    *(int4*)(&Qsh[swz(row, kc)]) = *(const int4*)(Qh + g);
    *(int4*)(&Qsl[swz(row, kc)]) = *(const int4*)(Ql + g);
  }
  __syncthreads();
  int fr = lane & 15, kof = (lane >> 4) << 3;
  bf16x8 aqh[2], aql[2];
  #pragma unroll
  for (int kf = 0; kf < 2; kf++) {
    aqh[kf] = *(const bf16x8*)(&Qsh[swz(w * 16 + fr, kf * 32 + kof)]);
    aql[kf] = *(const bf16x8*)(&Qsl[swz(w * 16 + fr, kf * 32 + kof)]);
  }

  f32x4 zero = {0.f, 0.f, 0.f, 0.f};
  f32x4 oacc[4];
  #pragma unroll
  for (int ni = 0; ni < 4; ni++) oacc[ni] = zero;
  float mrun[4], lrun[4];
  #pragma unroll
  for (int r = 0; r < 4; r++) { mrun[r] = -3.0e38f; lrun[r] = 0.f; }

  int srow = tid >> 3, skc = (tid & 7) << 3;
  const bf16* Kph = Kh + (xs + srow) * 256 + hd * 64 + skc;
  const bf16* Kpl = Kl + (xs + srow) * 256 + hd * 64 + skc;
  const bf16* Vph = Vth + ((size_t)sdb * 256 + hd * 64 + srow) * 2048 + skc;
  const bf16* Vpl = Vtl + ((size_t)sdb * 256 + hd * 64 + srow) * 2048 + skc;
  int4 ckh = *(const int4*)Kph;
  int4 ckl = *(const int4*)Kpl;
  int4 cvh = *(const int4*)Vph;
  int4 cvl = *(const int4*)Vpl;

  const float Cs = 0.18033688011112042f;  // log2(e)/8

  for (int m0 = 0; m0 < 2048; m0 += 64) {
    __syncthreads();
    *(int4*)(&Ksh[swz(srow, skc)]) = ckh;
    *(int4*)(&Ksl[swz(srow, skc)]) = ckl;
    *(int4*)(&Vsh[swz(srow, skc)]) = cvh;
    *(int4*)(&Vsl[swz(srow, skc)]) = cvl;
    if (m0 + 64 < 2048) {
      ckh = *(const int4*)(Kph + (size_t)(m0 + 64) * 256);
      ckl = *(const int4*)(Kpl + (size_t)(m0 + 64) * 256);
      cvh = *(const int4*)(Vph + m0 + 64);
      cvl = *(const int4*)(Vpl + m0 + 64);
    }
    __syncthreads();

    f32x4 sacc[4];
    #pragma unroll
    for (int ni = 0; ni < 4; ni++) sacc[ni] = zero;
    #pragma unroll
    for (int kf = 0; kf < 2; kf++) {
      #pragma unroll
      for (int ni = 0; ni < 4; ni++) {
        bf16x8 bkh = *(const bf16x8*)(&Ksh[swz(ni * 16 + fr, kf * 32 + kof)]);
        bf16x8 bkl = *(const bf16x8*)(&Ksl[swz(ni * 16 + fr, kf * 32 + kof)]);
        sacc[ni] = MFMA_BF16(aqh[kf], bkh, sacc[ni]);
        sacc[ni] = MFMA_BF16(aql[kf], bkh, sacc[ni]);
        sacc[ni] = MFMA_BF16(aqh[kf], bkl, sacc[ni]);
      }
    }

    #pragma unroll
    for (int r = 0; r < 4; r++) {
      float tm = fmaxf(fmaxf(sacc[0][r], sacc[1][r]), fmaxf(sacc[2][r], sacc[3][r]));
      tm = fmaxf(tm, __shfl_xor(tm, 1));
      tm = fmaxf(tm, __shfl_xor(tm, 2));
      tm = fmaxf(tm, __shfl_xor(tm, 4));
      tm = fmaxf(tm, __shfl_xor(tm, 8));
      float mn = fmaxf(mrun[r], tm);
      float sc = exp2f((mrun[r] - mn) * Cs);
      mrun[r] = mn;
      float rs = 0.f;
      #pragma unroll
      for (int ni = 0; ni < 4; ni++) {
        float pv = exp2f((sacc[ni][r] - mn) * Cs);
        sacc[ni][r] = pv;
        rs += pv;
      }
      rs += __shfl_xor(rs, 1);
      rs += __shfl_xor(rs, 2);
      rs += __shfl_xor(rs, 4);
      rs += __shfl_xor(rs, 8);
      lrun[r] = lrun[r] * sc + rs;
      #pragma unroll
      for (int ni = 0; ni < 4; ni++) oacc[ni][r] *= sc;
    }

    bf16* Pwh = &Psh[w * 16 * 64];
    bf16* Pwl = &Psl[w * 16 * 64];
    #pragma unroll
    for (int ni = 0; ni < 4; ni++) {
      int col = ni * 16 + fr;
      #pragma unroll
      for (int r = 0; r < 4; r++) {
        int row = ((lane >> 4) << 2) + r;
        float pv = sacc[ni][r];
        unsigned short hi = f2bf(pv);
        Pwh[swz(row, col)] = hi;
        Pwl[swz(row, col)] = f2bf(pv - bf2f(hi));
      }
    }
    #pragma unroll
    for (int kf = 0; kf < 2; kf++) {
      bf16x8 pah = *(const bf16x8*)(&Pwh[swz(fr, kf * 32 + kof)]);
      bf16x8 pal = *(const bf16x8*)(&Pwl[swz(fr, kf * 32 + kof)]);
      #pragma unroll
      for (int ni = 0; ni < 4; ni++) {
        bf16x8 bvh = *(const bf16x8*)(&Vsh[swz(ni * 16 + fr, kf * 32 + kof)]);
        bf16x8 bvl = *(const bf16x8*)(&Vsl[swz(ni * 16 + fr, kf * 32 + kof)]);
        oacc[ni] = MFMA_BF16(pah, bvh, oacc[ni]);
        oacc[ni] = MFMA_BF16(pal, bvh, oacc[ni]);
        oacc[ni] = MFMA_BF16(pah, bvl, oacc[ni]);
      }
    }
  }

  #pragma unroll
  for (int r = 0; r < 4; r++) {
    float inv = 1.0f / lrun[r];
    int nrow = n0 + w * 16 + ((lane >> 4) << 2) + r;
    #pragma unroll
    for (int ni = 0; ni < 4; ni++) {
      float v = oacc[ni][r] * inv;
      unsigned short hi = f2bf(v);
      size_t g = (xq + nrow) * 256 + hd * 64 + ni * 16 + fr;
      Oh[g] = hi;
      Ol[g] = f2bf(v - bf2f(hi));
    }
  }
}

// ---------------------------------------------------------------------------
extern "C" void kernel_launch(void* const* d_in, const int* in_sizes, int n_in,
                              void* d_out, int out_size, void* d_ws, size_t ws_size,
                              hipStream_t stream)
{
  (void)in_sizes; (void)n_in; (void)out_size; (void)ws_size;
  const float* desc0 = (const float*)d_in[0];
  const float* desc1 = (const float*)d_in[1];
  const float* Wq = (const float*)d_in[2];
  const float* bq = (const float*)d_in[3];
  const float* Wk = (const float*)d_in[4];
  const float* bk = (const float*)d_in[5];
  const float* Wv = (const float*)d_in[6];
  const float* bv = (const float*)d_in[7];
  const float* Wm = (const float*)d_in[8];
  const float* bm = (const float*)d_in[9];
  const float* W1 = (const float*)d_in[10];
  const float* b1 = (const float*)d_in[11];
  const float* gm = (const float*)d_in[12];
  const float* bt = (const float*)d_in[13];
  const float* W2 = (const float*)d_in[14];
  const float* b2 = (const float*)d_in[15];
  float* out = (float*)d_out;

  char* ws = (char*)d_ws;
  bf16*  Wbf  = (bf16*)(ws + 0);            //  31,457,280
  float* bias = (float*)(ws + 31457280);    //     110,592
  float* Dm   = (float*)(ws + 31567872);    //  16,777,216  fp32 master [xi,256]
  bf16*  Hin  = (bf16*)(ws + 48345088);     //  16,777,216  [xi,512] = xh | msg_h
  bf16*  XMl  = (bf16*)(ws + 65122304);     //  16,777,216  [xi,512] = xl | msg_l
  bf16*  Qh   = (bf16*)(ws + 81899520);     //   8,388,608
  bf16*  Ql   = (bf16*)(ws + 90288128);     //   8,388,608
  bf16*  Kh   = (bf16*)(ws + 98676736);     //   8,388,608
  bf16*  Kl   = (bf16*)(ws + 107065344);    //   8,388,608
  bf16*  Vth  = (bf16*)(ws + 115453952);    //   8,388,608  [db,256,2048]
  bf16*  Vtl  = (bf16*)(ws + 123842560);    //   8,388,608
  bf16*  Oh   = (bf16*)(ws + 132231168);    //   8,388,608
  bf16*  Ol   = (bf16*)(ws + 140619776);    //   8,388,608  -> end 149,008,384
  bf16*  Hbh  = Qh;                         //  16,777,216  alias Qh+Ql (disjoint in time)
  bf16*  Hbl  = Kh;                         //  16,777,216  alias Kh+Kl

  prep_weights<<<dim3(5130, 12), 256, 0, stream>>>(Wq, bq, Wk, bk, Wv, bv, Wm, bm,
                                                   W1, b1, gm, bt, W2, b2, Wbf, bias);
  transpose_in<<<dim3(64, 8, 4), dim3(32, 8), 0, stream>>>(desc0, desc1, Dm, Hin, XMl);

  for (int l = 0; l < NL; l++) {
    const bf16* wl = Wbf + (size_t)l * 1310720;
    const float* bl = bias + l * 2304;
    int cross = l & 1;
    // Q,K = x·Wq^T, x·Wk^T (rows 0:512 of Wqkv)
    gemm3<0><<<dim3(128, 4), 256, 0, stream>>>(Hin, 512, XMl, 512,
                                               wl, wl + 196608, 256,
                                               bl, nullptr, Qh, Ql, Kh, Kl, nullptr);
    // V (rows 512:768), transposed
    gemm3<1><<<dim3(128, 2), 256, 0, stream>>>(Hin, 512, XMl, 512,
                                               wl + 131072, wl + 196608 + 131072, 256,
                                               bl + 512, nullptr, Vth, Vtl, nullptr, nullptr, nullptr);
    attn3<<<dim3(16, 16), 512, 0, stream>>>(Qh, Ql, Kh, Kl, Vth, Vtl, Oh, Ol, cross);
    // merge: msg = O·Wm^T
    gemm3<2><<<dim3(128, 2), 256, 0, stream>>>(Oh, 256, Ol, 256,
                                               wl + 393216, wl + 458752, 256,
                                               bl + 768, nullptr, Hin, XMl, nullptr, nullptr, nullptr);
    // MLP1 + BN + ReLU
    gemm3<3><<<dim3(128, 4), 256, 0, stream>>>(Hin, 512, XMl, 512,
                                               wl + 524288, wl + 786432, 512,
                                               bl + 1024, bl + 1536, Hbh, Hbl, nullptr, nullptr, nullptr);
    // MLP2 + residual
    gemm3<4><<<dim3(128, 2), 256, 0, stream>>>(Hbh, 512, Hbl, 512,
                                               wl + 1048576, wl + 1179648, 512,
                                               bl + 2048, nullptr, Hin, XMl, nullptr, nullptr, Dm);
  }
  transpose_out<<<dim3(64, 8, 4), dim3(32, 8), 0, stream>>>(Dm, out);
}

// Round 5
// 2088.849 us; speedup vs baseline: 1.1624x; 1.1624x over previous
//
#include <hip/hip_runtime.h>

typedef unsigned short bf16;
typedef __attribute__((ext_vector_type(8))) short bf16x8;
typedef __attribute__((ext_vector_type(4))) float f32x4;
typedef unsigned short u16x4 __attribute__((ext_vector_type(4)));

#define DEVFN static __device__ __forceinline__

#define NL 12

DEVFN unsigned short f2bf(float f) {
  union { float f; unsigned u; } v; v.f = f;
  unsigned u = v.u;
  unsigned r = (u + 0x7fffu + ((u >> 16) & 1u)) >> 16;  // RNE
  return (unsigned short)r;
}
DEVFN float bf2f(unsigned short h) {
  union { unsigned u; float f; } v; v.u = ((unsigned)h) << 16; return v.f;
}

#define MFMA_BF16(a, b, c) __builtin_amdgcn_mfma_f32_16x16x32_bf16((a), (b), (c), 0, 0, 0)

// ---------------------------------------------------------------------------
// Weight prep: hi/lo bf16 split of every weight. Per-layer bf16 block (1310720):
//   [0,196608)         Wqkv hi (rows head-major permuted for q,k,v)
//   [196608,393216)    Wqkv lo
//   [393216,458752)    Wm hi (cols permuted)
//   [458752,524288)    Wm lo
//   [524288,786432)    W1 hi
//   [786432,1048576)   W1 lo
//   [1048576,1179648)  W2 hi
//   [1179648,1310720)  W2 lo
// Per-layer f32 bias block (2304): bqkv[768] | bm[256] | geff[512] | beff[512] | b2[256]
// ---------------------------------------------------------------------------
__global__ void prep_weights(const float* __restrict__ Wq, const float* __restrict__ bq,
                             const float* __restrict__ Wk, const float* __restrict__ bk,
                             const float* __restrict__ Wv, const float* __restrict__ bv,
                             const float* __restrict__ Wm, const float* __restrict__ bm,
                             const float* __restrict__ W1, const float* __restrict__ b1,
                             const float* __restrict__ gm, const float* __restrict__ bt,
                             const float* __restrict__ W2, const float* __restrict__ b2,
                             bf16* __restrict__ Wbf, float* __restrict__ bias)
{
  int l = blockIdx.y;
  bf16* wl = Wbf + (size_t)l * 1310720;
  float* bl = bias + l * 2304;
  int idx = blockIdx.x * blockDim.x + threadIdx.x;
  if (idx >= 1310720 + 2304) return;
  const float INV = 1.0f / sqrtf(1.0f + 1e-5f);

  float w = 0.f;
  int lo = 0;
  if (idx < 393216) {                         // Wqkv
    int j = idx; lo = (j >= 196608); j -= lo * 196608;
    int t = j >> 16;
    int p = (j >> 8) & 255;
    int k = j & 255;
    int c = ((p & 63) << 2) | (p >> 6);       // p = h*64+i -> c = i*4+h
    const float* W = (t == 0) ? Wq : (t == 1) ? Wk : Wv;
    w = W[(size_t)l * 65536 + c * 256 + k];
  } else if (idx < 524288) {                  // Wm (cols permuted)
    int j = idx - 393216; lo = (j >= 65536); j -= lo * 65536;
    int o = j >> 8, p = j & 255;
    int c = ((p & 63) << 2) | (p >> 6);
    w = Wm[(size_t)l * 65536 + o * 256 + c];
  } else if (idx < 1048576) {                 // W1
    int j = idx - 524288; lo = (j >= 262144); j &= 262143;
    w = W1[(size_t)l * 262144 + j];
  } else if (idx < 1310720) {                 // W2
    int j = idx - 1048576; lo = (j >= 131072); j &= 131071;
    w = W2[(size_t)l * 131072 + j];
  } else {
    int j = idx - 1310720;
    if (j < 768) {
      int t = j >> 8, p = j & 255;
      int c = ((p & 63) << 2) | (p >> 6);
      const float* bsrc = (t == 0) ? bq : (t == 1) ? bk : bv;
      bl[j] = bsrc[l * 256 + c];
    } else if (j < 1024) {
      bl[j] = bm[l * 256 + (j - 768)];
    } else if (j < 1536) {
      bl[j] = gm[l * 512 + (j - 1024)] * INV;
    } else if (j < 2048) {
      int o = j - 1536;
      bl[j] = gm[l * 512 + o] * INV * b1[l * 512 + o] + bt[l * 512 + o];
    } else {
      bl[j] = b2[l * 256 + (j - 2048)];
    }
    return;
  }
  unsigned short hi = f2bf(w);
  wl[idx] = lo ? f2bf(w - bf2f(hi)) : hi;
}

// ---------------------------------------------------------------------------
// Input transpose: desc [b,d,n] fp32 -> Dm [xi,256] fp32; Hin[:,0:256]=x hi;
// XMl[:,0:256]=x lo (both lda 512).
// ---------------------------------------------------------------------------
__global__ void transpose_in(const float* __restrict__ s0, const float* __restrict__ s1,
                             float* __restrict__ Dm, bf16* __restrict__ Hin,
                             bf16* __restrict__ XMl)
{
  __shared__ float t[32][33];
  int db = blockIdx.z;
  int dsc = db >> 1, bi = db & 1;
  const float* src = dsc ? s1 : s0;
  int n0 = blockIdx.x * 32, d0 = blockIdx.y * 32;
  int tx = threadIdx.x, ty = threadIdx.y;
  #pragma unroll
  for (int i = 0; i < 32; i += 8)
    t[ty + i][tx] = src[(size_t)(bi * 256 + d0 + ty + i) * 2048 + n0 + tx];
  __syncthreads();
  #pragma unroll
  for (int i = 0; i < 32; i += 8) {
    size_t xi = (size_t)db * 2048 + n0 + ty + i;
    float v = t[tx][ty + i];
    Dm[xi * 256 + d0 + tx] = v;
    unsigned short hi = f2bf(v);
    Hin[xi * 512 + d0 + tx] = hi;
    XMl[xi * 512 + d0 + tx] = f2bf(v - bf2f(hi));
  }
}

__global__ void transpose_out(const float* __restrict__ Dm, float* __restrict__ out)
{
  __shared__ float t[32][33];
  int db = blockIdx.z;
  int n0 = blockIdx.x * 32, d0 = blockIdx.y * 32;
  int tx = threadIdx.x, ty = threadIdx.y;
  #pragma unroll
  for (int i = 0; i < 32; i += 8)
    t[ty + i][tx] = Dm[((size_t)db * 2048 + n0 + ty + i) * 256 + d0 + tx];
  __syncthreads();
  #pragma unroll
  for (int i = 0; i < 32; i += 8)
    out[(size_t)(db * 256 + d0 + ty + i) * 2048 + n0 + tx] = t[tx][ty + i];
}

// ---------------------------------------------------------------------------
// 3-term split GEMM: C = Ah·Wh^T + Al·Wh^T + Ah·Wl^T  (~fp32 accuracy)
// Tile 128x128, BK=32, 4 waves. Granule-XOR-swizzled LDS (64B rows).
// EPI 0: Q/K  -> hi/lo (o0..o3 = Qh,Ql,Kh,Kl), +bias
// EPI 1: V    -> Vt hi/lo transposed [db,256,2048], +bias
// EPI 2: merge-> Hin[:,256:512] hi, XMl[:,256:512] lo, +bias
// EPI 3: MLP1 -> BN+ReLU, Hbh/Hbl [xi,512]
// EPI 4: MLP2 -> Dm += acc+b2 (fp32); Hin[:,0:256] hi, XMl[:,0:256] lo
// ---------------------------------------------------------------------------
DEVFN int gsw(int row, int col) { return row * 32 + (col ^ ((row & 3) << 3)); }

template<int EPI>
__global__ __launch_bounds__(256) void gemm3(
    const bf16* __restrict__ Ah, int lda,
    const bf16* __restrict__ Al, int ldal,
    const bf16* __restrict__ Wh, const bf16* __restrict__ Wl, int K,
    const float* __restrict__ b0, const float* __restrict__ b1,
    bf16* __restrict__ o0, bf16* __restrict__ o1,
    bf16* __restrict__ o2, bf16* __restrict__ o3,
    float* __restrict__ of)
{
  __shared__ bf16 AsH[128 * 32];
  __shared__ bf16 AsL[128 * 32];
  __shared__ bf16 BsH[128 * 32];
  __shared__ bf16 BsL[128 * 32];
  int tid = threadIdx.x, lane = tid & 63, wid = tid >> 6;
  int wr = wid >> 1, wc = wid & 1;
  int m0 = blockIdx.x * 128, n0 = blockIdx.y * 128;
  int r0 = tid >> 2, kc0 = (tid & 3) << 3;
  const bf16* Aph = Ah + (size_t)(m0 + r0) * lda + kc0;
  const bf16* Apl = Al + (size_t)(m0 + r0) * ldal + kc0;
  const bf16* Wph = Wh + (size_t)(n0 + r0) * K + kc0;
  const bf16* Wpl = Wl + (size_t)(n0 + r0) * K + kc0;
  size_t ah_s = (size_t)64 * lda, al_s = (size_t)64 * ldal, w_s = (size_t)64 * K;

  f32x4 zero = {0.f, 0.f, 0.f, 0.f};
  f32x4 acc[4][4];
  #pragma unroll
  for (int i = 0; i < 4; i++)
    #pragma unroll
    for (int j = 0; j < 4; j++) acc[i][j] = zero;

  int4 ah0 = *(const int4*)Aph, ah1 = *(const int4*)(Aph + ah_s);
  int4 al0 = *(const int4*)Apl, al1 = *(const int4*)(Apl + al_s);
  int4 bh0 = *(const int4*)Wph, bh1 = *(const int4*)(Wph + w_s);
  int4 bl0 = *(const int4*)Wpl, bl1 = *(const int4*)(Wpl + w_s);

  int fr = lane & 15, kof = (lane >> 4) << 3;
  for (int k0 = 0; k0 < K; k0 += 32) {
    __syncthreads();
    *(int4*)(&AsH[gsw(r0, kc0)]) = ah0;
    *(int4*)(&AsH[gsw(64 + r0, kc0)]) = ah1;
    *(int4*)(&AsL[gsw(r0, kc0)]) = al0;
    *(int4*)(&AsL[gsw(64 + r0, kc0)]) = al1;
    *(int4*)(&BsH[gsw(r0, kc0)]) = bh0;
    *(int4*)(&BsH[gsw(64 + r0, kc0)]) = bh1;
    *(int4*)(&BsL[gsw(r0, kc0)]) = bl0;
    *(int4*)(&BsL[gsw(64 + r0, kc0)]) = bl1;
    if (k0 + 32 < K) {
      ah0 = *(const int4*)(Aph + k0 + 32);
      ah1 = *(const int4*)(Aph + k0 + 32 + ah_s);
      al0 = *(const int4*)(Apl + k0 + 32);
      al1 = *(const int4*)(Apl + k0 + 32 + al_s);
      bh0 = *(const int4*)(Wph + k0 + 32);
      bh1 = *(const int4*)(Wph + k0 + 32 + w_s);
      bl0 = *(const int4*)(Wpl + k0 + 32);
      bl1 = *(const int4*)(Wpl + k0 + 32 + w_s);
    }
    __syncthreads();
    bf16x8 afh[4], afl[4], bfh[4], bfl[4];
    #pragma unroll
    for (int i = 0; i < 4; i++) {
      afh[i] = *(const bf16x8*)(&AsH[gsw(wr * 64 + i * 16 + fr, kof)]);
      afl[i] = *(const bf16x8*)(&AsL[gsw(wr * 64 + i * 16 + fr, kof)]);
      bfh[i] = *(const bf16x8*)(&BsH[gsw(wc * 64 + i * 16 + fr, kof)]);
      bfl[i] = *(const bf16x8*)(&BsL[gsw(wc * 64 + i * 16 + fr, kof)]);
    }
    #pragma unroll
    for (int mi = 0; mi < 4; mi++)
      #pragma unroll
      for (int ni = 0; ni < 4; ni++) {
        acc[mi][ni] = MFMA_BF16(afh[mi], bfh[ni], acc[mi][ni]);
        acc[mi][ni] = MFMA_BF16(afl[mi], bfh[ni], acc[mi][ni]);
        acc[mi][ni] = MFMA_BF16(afh[mi], bfl[ni], acc[mi][ni]);
      }
  }

  #pragma unroll
  for (int mi = 0; mi < 4; mi++) {
    #pragma unroll
    for (int ni = 0; ni < 4; ni++) {
      int mrow = m0 + wr * 64 + mi * 16 + ((lane >> 4) << 2);
      int ocol = n0 + wc * 64 + ni * 16 + fr;
      if constexpr (EPI == 0) {          // Q/K hi+lo
        float bb = b0[ocol];
        bf16* Dh = (ocol < 256) ? o0 : o2;
        bf16* Dl = (ocol < 256) ? o1 : o3;
        int oo = ocol & 255;
        #pragma unroll
        for (int r = 0; r < 4; r++) {
          float v = acc[mi][ni][r] + bb;
          unsigned short hi = f2bf(v);
          Dh[(size_t)(mrow + r) * 256 + oo] = hi;
          Dl[(size_t)(mrow + r) * 256 + oo] = f2bf(v - bf2f(hi));
        }
      } else if constexpr (EPI == 1) {   // V transposed hi+lo
        float bb = b0[ocol];
        int dbi = mrow >> 11, nn = mrow & 2047;
        u16x4 ph, pl;
        #pragma unroll
        for (int r = 0; r < 4; r++) {
          float v = acc[mi][ni][r] + bb;
          unsigned short hi = f2bf(v);
          ph[r] = hi;
          pl[r] = f2bf(v - bf2f(hi));
        }
        *(u16x4*)(&o0[((size_t)dbi * 256 + ocol) * 2048 + nn]) = ph;
        *(u16x4*)(&o1[((size_t)dbi * 256 + ocol) * 2048 + nn]) = pl;
      } else if constexpr (EPI == 2) {   // merge -> msg hi+lo
        float bb = b0[ocol];
        #pragma unroll
        for (int r = 0; r < 4; r++) {
          float v = acc[mi][ni][r] + bb;
          unsigned short hi = f2bf(v);
          o0[(size_t)(mrow + r) * 512 + 256 + ocol] = hi;
          o1[(size_t)(mrow + r) * 512 + 256 + ocol] = f2bf(v - bf2f(hi));
        }
      } else if constexpr (EPI == 3) {   // BN+ReLU hi+lo
        float ge = b0[ocol], be = b1[ocol];
        #pragma unroll
        for (int r = 0; r < 4; r++) {
          float v = fmaxf(ge * acc[mi][ni][r] + be, 0.f);
          unsigned short hi = f2bf(v);
          o0[(size_t)(mrow + r) * 512 + ocol] = hi;
          o1[(size_t)(mrow + r) * 512 + ocol] = f2bf(v - bf2f(hi));
        }
      } else {                           // EPI 4: residual
        float bb = b0[ocol];
        #pragma unroll
        for (int r = 0; r < 4; r++) {
          size_t ix = (size_t)(mrow + r) * 256 + ocol;
          float d = of[ix] + acc[mi][ni][r] + bb;
          of[ix] = d;
          unsigned short hi = f2bf(d);
          o0[(size_t)(mrow + r) * 512 + ocol] = hi;
          o1[(size_t)(mrow + r) * 512 + ocol] = f2bf(d - bf2f(hi));
        }
      }
    }
  }
}

// ---------------------------------------------------------------------------
// Flash attention, full split precision: 3-term QK^T and 3-term PV.
// Grid (16 n-blocks, 16 inst), 512 threads. QB=128, KB=64, dh=64.
// Q hi/lo direct global->reg (no LDS). K/V single-buffer LDS + reg prefetch.
// Row-sum via ones-MFMA (2 MFMA replace 16 shfl+add). LDS 64KB -> 2 blocks/CU.
// ---------------------------------------------------------------------------
DEVFN int swz(int row, int col) { return row * 64 + (col ^ ((row & 7) << 3)); }

__global__ __launch_bounds__(512) void attn3(
    const bf16* __restrict__ Qh, const bf16* __restrict__ Ql,
    const bf16* __restrict__ Kh, const bf16* __restrict__ Kl,
    const bf16* __restrict__ Vth, const bf16* __restrict__ Vtl,
    bf16* __restrict__ Oh, bf16* __restrict__ Ol, int cross)
{
  __shared__ bf16 Ksh[64 * 64];
  __shared__ bf16 Ksl[64 * 64];
  __shared__ bf16 Vsh[64 * 64];
  __shared__ bf16 Vsl[64 * 64];
  __shared__ bf16 Psh[8][16 * 64];
  __shared__ bf16 Psl[8][16 * 64];
  int tid = threadIdx.x, lane = tid & 63, w = tid >> 6;
  int inst = blockIdx.y;
  int db = inst >> 2, hd = inst & 3;
  int dsc = db >> 1, bi = db & 1;
  int sdb = (cross ? (1 - dsc) : dsc) * 2 + bi;
  size_t xq = (size_t)db * 2048;
  size_t xs = (size_t)sdb * 2048;
  int n0 = blockIdx.x * 128;

  int fr = lane & 15, kof = (lane >> 4) << 3;

  // Q fragments hi/lo: direct global -> registers
  bf16x8 aqh[2], aql[2];
  #pragma unroll
  for (int kf = 0; kf < 2; kf++) {
    size_t g = (xq + n0 + w * 16 + fr) * 256 + hd * 64 + kf * 32 + kof;
    aqh[kf] = *(const bf16x8*)(Qh + g);
    aql[kf] = *(const bf16x8*)(Ql + g);
  }

  f32x4 zero = {0.f, 0.f, 0.f, 0.f};
  f32x4 oacc[4];
  #pragma unroll
  for (int ni = 0; ni < 4; ni++) oacc[ni] = zero;
  float mrun[4], lrun[4];
  #pragma unroll
  for (int r = 0; r < 4; r++) { mrun[r] = -3.0e38f; lrun[r] = 0.f; }

  bf16x8 vone;
  #pragma unroll
  for (int i = 0; i < 8; i++) vone[i] = (short)0x3F80;  // bf16 1.0

  int srow = tid >> 3, skc = (tid & 7) << 3;
  const bf16* Kph = Kh + (xs + srow) * 256 + hd * 64 + skc;
  const bf16* Kpl = Kl + (xs + srow) * 256 + hd * 64 + skc;
  const bf16* Vph = Vth + ((size_t)sdb * 256 + hd * 64 + srow) * 2048 + skc;
  const bf16* Vpl = Vtl + ((size_t)sdb * 256 + hd * 64 + srow) * 2048 + skc;
  int4 ckh = *(const int4*)Kph;
  int4 ckl = *(const int4*)Kpl;
  int4 cvh = *(const int4*)Vph;
  int4 cvl = *(const int4*)Vpl;

  const float Cs = 0.18033688011112042f;  // log2(e)/8

  for (int m0 = 0; m0 < 2048; m0 += 64) {
    __syncthreads();
    *(int4*)(&Ksh[swz(srow, skc)]) = ckh;
    *(int4*)(&Ksl[swz(srow, skc)]) = ckl;
    *(int4*)(&Vsh[swz(srow, skc)]) = cvh;
    *(int4*)(&Vsl[swz(srow, skc)]) = cvl;
    if (m0 + 64 < 2048) {
      ckh = *(const int4*)(Kph + (size_t)(m0 + 64) * 256);
      ckl = *(const int4*)(Kpl + (size_t)(m0 + 64) * 256);
      cvh = *(const int4*)(Vph + m0 + 64);
      cvl = *(const int4*)(Vpl + m0 + 64);
    }
    __syncthreads();

    f32x4 sacc[4];
    #pragma unroll
    for (int ni = 0; ni < 4; ni++) sacc[ni] = zero;
    #pragma unroll
    for (int kf = 0; kf < 2; kf++) {
      #pragma unroll
      for (int ni = 0; ni < 4; ni++) {
        bf16x8 bkh = *(const bf16x8*)(&Ksh[swz(ni * 16 + fr, kf * 32 + kof)]);
        bf16x8 bkl = *(const bf16x8*)(&Ksl[swz(ni * 16 + fr, kf * 32 + kof)]);
        sacc[ni] = MFMA_BF16(aqh[kf], bkh, sacc[ni]);
        sacc[ni] = MFMA_BF16(aql[kf], bkh, sacc[ni]);
        sacc[ni] = MFMA_BF16(aqh[kf], bkl, sacc[ni]);
      }
    }

    float sc[4];
    #pragma unroll
    for (int r = 0; r < 4; r++) {
      float tm = fmaxf(fmaxf(sacc[0][r], sacc[1][r]), fmaxf(sacc[2][r], sacc[3][r]));
      tm = fmaxf(tm, __shfl_xor(tm, 1));
      tm = fmaxf(tm, __shfl_xor(tm, 2));
      tm = fmaxf(tm, __shfl_xor(tm, 4));
      tm = fmaxf(tm, __shfl_xor(tm, 8));
      float mn = fmaxf(mrun[r], tm);
      sc[r] = exp2f((mrun[r] - mn) * Cs);
      mrun[r] = mn;
      #pragma unroll
      for (int ni = 0; ni < 4; ni++)
        sacc[ni][r] = exp2f((sacc[ni][r] - mn) * Cs);
      #pragma unroll
      for (int ni = 0; ni < 4; ni++) oacc[ni][r] *= sc[r];
    }

    bf16* Pwh = &Psh[w][0];
    bf16* Pwl = &Psl[w][0];
    #pragma unroll
    for (int ni = 0; ni < 4; ni++) {
      int col = ni * 16 + fr;
      #pragma unroll
      for (int r = 0; r < 4; r++) {
        int row = ((lane >> 4) << 2) + r;
        float pv = sacc[ni][r];
        unsigned short hi = f2bf(pv);
        Pwh[swz(row, col)] = hi;
        Pwl[swz(row, col)] = f2bf(pv - bf2f(hi));
      }
    }

    // PV (3-term) + row-sum via ones-MFMA
    f32x4 racc = zero;
    #pragma unroll
    for (int kf = 0; kf < 2; kf++) {
      bf16x8 pah = *(const bf16x8*)(&Pwh[swz(fr, kf * 32 + kof)]);
      bf16x8 pal = *(const bf16x8*)(&Pwl[swz(fr, kf * 32 + kof)]);
      #pragma unroll
      for (int ni = 0; ni < 4; ni++) {
        bf16x8 bvh = *(const bf16x8*)(&Vsh[swz(ni * 16 + fr, kf * 32 + kof)]);
        bf16x8 bvl = *(const bf16x8*)(&Vsl[swz(ni * 16 + fr, kf * 32 + kof)]);
        oacc[ni] = MFMA_BF16(pah, bvh, oacc[ni]);
        oacc[ni] = MFMA_BF16(pal, bvh, oacc[ni]);
        oacc[ni] = MFMA_BF16(pah, bvl, oacc[ni]);
      }
      racc = MFMA_BF16(pah, vone, racc);
      racc = MFMA_BF16(pal, vone, racc);
    }
    #pragma unroll
    for (int r = 0; r < 4; r++)
      lrun[r] = lrun[r] * sc[r] + racc[r];
  }

  #pragma unroll
  for (int r = 0; r < 4; r++) {
    float inv = 1.0f / lrun[r];
    int nrow = n0 + w * 16 + ((lane >> 4) << 2) + r;
    #pragma unroll
    for (int ni = 0; ni < 4; ni++) {
      float v = oacc[ni][r] * inv;
      unsigned short hi = f2bf(v);
      size_t g = (xq + nrow) * 256 + hd * 64 + ni * 16 + fr;
      Oh[g] = hi;
      Ol[g] = f2bf(v - bf2f(hi));
    }
  }
}

// ---------------------------------------------------------------------------
extern "C" void kernel_launch(void* const* d_in, const int* in_sizes, int n_in,
                              void* d_out, int out_size, void* d_ws, size_t ws_size,
                              hipStream_t stream)
{
  (void)in_sizes; (void)n_in; (void)out_size; (void)ws_size;
  const float* desc0 = (const float*)d_in[0];
  const float* desc1 = (const float*)d_in[1];
  const float* Wq = (const float*)d_in[2];
  const float* bq = (const float*)d_in[3];
  const float* Wk = (const float*)d_in[4];
  const float* bk = (const float*)d_in[5];
  const float* Wv = (const float*)d_in[6];
  const float* bv = (const float*)d_in[7];
  const float* Wm = (const float*)d_in[8];
  const float* bm = (const float*)d_in[9];
  const float* W1 = (const float*)d_in[10];
  const float* b1 = (const float*)d_in[11];
  const float* gm = (const float*)d_in[12];
  const float* bt = (const float*)d_in[13];
  const float* W2 = (const float*)d_in[14];
  const float* b2 = (const float*)d_in[15];
  float* out = (float*)d_out;

  char* ws = (char*)d_ws;
  bf16*  Wbf  = (bf16*)(ws + 0);            //  31,457,280
  float* bias = (float*)(ws + 31457280);    //     110,592
  float* Dm   = (float*)(ws + 31567872);    //  16,777,216  fp32 master [xi,256]
  bf16*  Hin  = (bf16*)(ws + 48345088);     //  16,777,216  [xi,512] = xh | msg_h
  bf16*  XMl  = (bf16*)(ws + 65122304);     //  16,777,216  [xi,512] = xl | msg_l
  bf16*  Qh   = (bf16*)(ws + 81899520);     //   8,388,608
  bf16*  Ql   = (bf16*)(ws + 90288128);     //   8,388,608
  bf16*  Kh   = (bf16*)(ws + 98676736);     //   8,388,608
  bf16*  Kl   = (bf16*)(ws + 107065344);    //   8,388,608
  bf16*  Vth  = (bf16*)(ws + 115453952);    //   8,388,608  [db,256,2048]
  bf16*  Vtl  = (bf16*)(ws + 123842560);    //   8,388,608
  bf16*  Oh   = (bf16*)(ws + 132231168);    //   8,388,608
  bf16*  Ol   = (bf16*)(ws + 140619776);    //   8,388,608  -> end 149,008,384
  bf16*  Hbh  = Qh;                         //  16,777,216  alias Qh+Ql (disjoint in time)
  bf16*  Hbl  = Kh;                         //  16,777,216  alias Kh+Kl

  prep_weights<<<dim3(5130, 12), 256, 0, stream>>>(Wq, bq, Wk, bk, Wv, bv, Wm, bm,
                                                   W1, b1, gm, bt, W2, b2, Wbf, bias);
  transpose_in<<<dim3(64, 8, 4), dim3(32, 8), 0, stream>>>(desc0, desc1, Dm, Hin, XMl);

  for (int l = 0; l < NL; l++) {
    const bf16* wl = Wbf + (size_t)l * 1310720;
    const float* bl = bias + l * 2304;
    int cross = l & 1;
    // Q,K = x·Wq^T, x·Wk^T (rows 0:512 of Wqkv)   [xi = 8192 rows -> 64 blocks]
    gemm3<0><<<dim3(64, 4), 256, 0, stream>>>(Hin, 512, XMl, 512,
                                              wl, wl + 196608, 256,
                                              bl, nullptr, Qh, Ql, Kh, Kl, nullptr);
    // V (rows 512:768), transposed
    gemm3<1><<<dim3(64, 2), 256, 0, stream>>>(Hin, 512, XMl, 512,
                                              wl + 131072, wl + 196608 + 131072, 256,
                                              bl + 512, nullptr, Vth, Vtl, nullptr, nullptr, nullptr);
    attn3<<<dim3(16, 16), 512, 0, stream>>>(Qh, Ql, Kh, Kl, Vth, Vtl, Oh, Ol, cross);
    // merge: msg = O·Wm^T
    gemm3<2><<<dim3(64, 2), 256, 0, stream>>>(Oh, 256, Ol, 256,
                                              wl + 393216, wl + 458752, 256,
                                              bl + 768, nullptr, Hin, XMl, nullptr, nullptr, nullptr);
    // MLP1 + BN + ReLU
    gemm3<3><<<dim3(64, 4), 256, 0, stream>>>(Hin, 512, XMl, 512,
                                              wl + 524288, wl + 786432, 512,
                                              bl + 1024, bl + 1536, Hbh, Hbl, nullptr, nullptr, nullptr);
    // MLP2 + residual
    gemm3<4><<<dim3(64, 2), 256, 0, stream>>>(Hbh, 512, Hbl, 512,
                                              wl + 1048576, wl + 1179648, 512,
                                              bl + 2048, nullptr, Hin, XMl, nullptr, nullptr, Dm);
  }
  transpose_out<<<dim3(64, 8, 4), dim3(32, 8), 0, stream>>>(Dm, out);
}

// Round 6
// 1957.942 us; speedup vs baseline: 1.2401x; 1.0669x over previous
//
#include <hip/hip_runtime.h>

typedef unsigned short bf16;
typedef __attribute__((ext_vector_type(8))) short bf16x8;
typedef __attribute__((ext_vector_type(4))) float f32x4;
typedef unsigned short u16x4 __attribute__((ext_vector_type(4)));

#define DEVFN static __device__ __forceinline__

#define NL 12

DEVFN unsigned short f2bf(float f) {
  union { float f; unsigned u; } v; v.f = f;
  unsigned u = v.u;
  unsigned r = (u + 0x7fffu + ((u >> 16) & 1u)) >> 16;  // RNE
  return (unsigned short)r;
}
DEVFN float bf2f(unsigned short h) {
  union { unsigned u; float f; } v; v.u = ((unsigned)h) << 16; return v.f;
}

#define MFMA_BF16(a, b, c) __builtin_amdgcn_mfma_f32_16x16x32_bf16((a), (b), (c), 0, 0, 0)

// ---------------------------------------------------------------------------
// Weight prep: hi/lo bf16 split of every weight. Wq rows and bq are pre-scaled
// by Cs = log2(e)/8 so attention scores are already in exp2 units.
// Per-layer bf16 block (1310720):
//   [0,196608)         Wqkv hi (rows head-major permuted; q,k,v)
//   [196608,393216)    Wqkv lo
//   [393216,458752)    Wm hi (cols permuted)
//   [458752,524288)    Wm lo
//   [524288,786432)    W1 hi
//   [786432,1048576)   W1 lo
//   [1048576,1179648)  W2 hi
//   [1179648,1310720)  W2 lo
// Per-layer f32 bias block (2304): bqkv[768] | bm[256] | geff[512] | beff[512] | b2[256]
// ---------------------------------------------------------------------------
__global__ void prep_weights(const float* __restrict__ Wq, const float* __restrict__ bq,
                             const float* __restrict__ Wk, const float* __restrict__ bk,
                             const float* __restrict__ Wv, const float* __restrict__ bv,
                             const float* __restrict__ Wm, const float* __restrict__ bm,
                             const float* __restrict__ W1, const float* __restrict__ b1,
                             const float* __restrict__ gm, const float* __restrict__ bt,
                             const float* __restrict__ W2, const float* __restrict__ b2,
                             bf16* __restrict__ Wbf, float* __restrict__ bias)
{
  int l = blockIdx.y;
  bf16* wl = Wbf + (size_t)l * 1310720;
  float* bl = bias + l * 2304;
  int idx = blockIdx.x * blockDim.x + threadIdx.x;
  if (idx >= 1310720 + 2304) return;
  const float INV = 1.0f / sqrtf(1.0f + 1e-5f);
  const float Cs = 0.18033688011112042f;  // log2(e)/8

  float w = 0.f;
  int lo = 0;
  if (idx < 393216) {                         // Wqkv
    int j = idx; lo = (j >= 196608); j -= lo * 196608;
    int t = j >> 16;
    int p = (j >> 8) & 255;
    int k = j & 255;
    int c = ((p & 63) << 2) | (p >> 6);       // p = h*64+i -> c = i*4+h
    const float* W = (t == 0) ? Wq : (t == 1) ? Wk : Wv;
    w = W[(size_t)l * 65536 + c * 256 + k];
    if (t == 0) w *= Cs;                      // fold score scale into Q
  } else if (idx < 524288) {                  // Wm (cols permuted)
    int j = idx - 393216; lo = (j >= 65536); j -= lo * 65536;
    int o = j >> 8, p = j & 255;
    int c = ((p & 63) << 2) | (p >> 6);
    w = Wm[(size_t)l * 65536 + o * 256 + c];
  } else if (idx < 1048576) {                 // W1
    int j = idx - 524288; lo = (j >= 262144); j &= 262143;
    w = W1[(size_t)l * 262144 + j];
  } else if (idx < 1310720) {                 // W2
    int j = idx - 1048576; lo = (j >= 131072); j &= 131071;
    w = W2[(size_t)l * 131072 + j];
  } else {
    int j = idx - 1310720;
    if (j < 768) {
      int t = j >> 8, p = j & 255;
      int c = ((p & 63) << 2) | (p >> 6);
      const float* bsrc = (t == 0) ? bq : (t == 1) ? bk : bv;
      bl[j] = bsrc[l * 256 + c] * ((t == 0) ? Cs : 1.0f);
    } else if (j < 1024) {
      bl[j] = bm[l * 256 + (j - 768)];
    } else if (j < 1536) {
      bl[j] = gm[l * 512 + (j - 1024)] * INV;
    } else if (j < 2048) {
      int o = j - 1536;
      bl[j] = gm[l * 512 + o] * INV * b1[l * 512 + o] + bt[l * 512 + o];
    } else {
      bl[j] = b2[l * 256 + (j - 2048)];
    }
    return;
  }
  unsigned short hi = f2bf(w);
  wl[idx] = lo ? f2bf(w - bf2f(hi)) : hi;
}

// ---------------------------------------------------------------------------
// Input transpose: desc [b,d,n] fp32 -> Dm [xi,256] fp32; Hin[:,0:256]=x hi;
// XMl[:,0:256]=x lo (both lda 512).
// ---------------------------------------------------------------------------
__global__ void transpose_in(const float* __restrict__ s0, const float* __restrict__ s1,
                             float* __restrict__ Dm, bf16* __restrict__ Hin,
                             bf16* __restrict__ XMl)
{
  __shared__ float t[32][33];
  int db = blockIdx.z;
  int dsc = db >> 1, bi = db & 1;
  const float* src = dsc ? s1 : s0;
  int n0 = blockIdx.x * 32, d0 = blockIdx.y * 32;
  int tx = threadIdx.x, ty = threadIdx.y;
  #pragma unroll
  for (int i = 0; i < 32; i += 8)
    t[ty + i][tx] = src[(size_t)(bi * 256 + d0 + ty + i) * 2048 + n0 + tx];
  __syncthreads();
  #pragma unroll
  for (int i = 0; i < 32; i += 8) {
    size_t xi = (size_t)db * 2048 + n0 + ty + i;
    float v = t[tx][ty + i];
    Dm[xi * 256 + d0 + tx] = v;
    unsigned short hi = f2bf(v);
    Hin[xi * 512 + d0 + tx] = hi;
    XMl[xi * 512 + d0 + tx] = f2bf(v - bf2f(hi));
  }
}

__global__ void transpose_out(const float* __restrict__ Dm, float* __restrict__ out)
{
  __shared__ float t[32][33];
  int db = blockIdx.z;
  int n0 = blockIdx.x * 32, d0 = blockIdx.y * 32;
  int tx = threadIdx.x, ty = threadIdx.y;
  #pragma unroll
  for (int i = 0; i < 32; i += 8)
    t[ty + i][tx] = Dm[((size_t)db * 2048 + n0 + ty + i) * 256 + d0 + tx];
  __syncthreads();
  #pragma unroll
  for (int i = 0; i < 32; i += 8)
    out[(size_t)(db * 256 + d0 + ty + i) * 2048 + n0 + tx] = t[tx][ty + i];
}

// ---------------------------------------------------------------------------
// 3-term split GEMM: C = Ah·Wh^T + Al·Wh^T + Ah·Wl^T  (~fp32 accuracy)
// Tile 128xNT (NT=128 or 64), BK=32, 4 waves (2x2). Granule-XOR-swizzled LDS.
// EPI 0 (NT=128): fused QKV -> Q hi/lo (o0,o1; pre-scaled), K hi/lo (o2,o3),
//                 V hi/lo transposed [db,256,2048] (o4,o5); +bias
// EPI 2 (NT=64):  merge -> Hin[:,256:512] hi (o0), XMl lo (o1), +bias
// EPI 3 (NT=128): MLP1 -> BN+ReLU, o0/o1 = Hbh/Hbl [xi,512]
// EPI 4 (NT=64):  MLP2 -> Dm += acc+b2 (fp32, of); o0/o1 = Hin/XMl[:,0:256]
// ---------------------------------------------------------------------------
DEVFN int gsw(int row, int col) { return row * 32 + (col ^ ((row & 3) << 3)); }

template<int EPI, int NT>
__global__ __launch_bounds__(256) void gemm3(
    const bf16* __restrict__ Ah, int lda,
    const bf16* __restrict__ Al, int ldal,
    const bf16* __restrict__ Wh, const bf16* __restrict__ Wl, int K,
    const float* __restrict__ b0, const float* __restrict__ b1,
    bf16* __restrict__ o0, bf16* __restrict__ o1,
    bf16* __restrict__ o2, bf16* __restrict__ o3,
    bf16* __restrict__ o4, bf16* __restrict__ o5,
    float* __restrict__ of)
{
  constexpr int NFR = NT / 32;          // B frags per wave
  __shared__ bf16 AsH[128 * 32];
  __shared__ bf16 AsL[128 * 32];
  __shared__ bf16 BsH[NT * 32];
  __shared__ bf16 BsL[NT * 32];
  int tid = threadIdx.x, lane = tid & 63, wid = tid >> 6;
  int wr = wid >> 1, wc = wid & 1;
  int m0 = blockIdx.x * 128, n0 = blockIdx.y * NT;
  int r0 = tid >> 2, kc0 = (tid & 3) << 3;
  const bf16* Aph = Ah + (size_t)(m0 + r0) * lda + kc0;
  const bf16* Apl = Al + (size_t)(m0 + r0) * ldal + kc0;
  const bf16* Wph = Wh + (size_t)(n0 + r0) * K + kc0;
  const bf16* Wpl = Wl + (size_t)(n0 + r0) * K + kc0;
  size_t ah_s = (size_t)64 * lda, al_s = (size_t)64 * ldal, w_s = (size_t)64 * K;

  f32x4 zero = {0.f, 0.f, 0.f, 0.f};
  f32x4 acc[4][NFR];
  #pragma unroll
  for (int i = 0; i < 4; i++)
    #pragma unroll
    for (int j = 0; j < NFR; j++) acc[i][j] = zero;

  int4 ah0 = *(const int4*)Aph, ah1 = *(const int4*)(Aph + ah_s);
  int4 al0 = *(const int4*)Apl, al1 = *(const int4*)(Apl + al_s);
  int4 bh0 = *(const int4*)Wph;
  int4 bl0 = *(const int4*)Wpl;
  int4 bh1 = {}, bl1 = {};
  if constexpr (NT == 128) {
    bh1 = *(const int4*)(Wph + w_s);
    bl1 = *(const int4*)(Wpl + w_s);
  }

  int fr = lane & 15, kof = (lane >> 4) << 3;
  int cb = wc * (NT / 2);
  for (int k0 = 0; k0 < K; k0 += 32) {
    __syncthreads();
    *(int4*)(&AsH[gsw(r0, kc0)]) = ah0;
    *(int4*)(&AsH[gsw(64 + r0, kc0)]) = ah1;
    *(int4*)(&AsL[gsw(r0, kc0)]) = al0;
    *(int4*)(&AsL[gsw(64 + r0, kc0)]) = al1;
    if constexpr (NT == 128) {
      *(int4*)(&BsH[gsw(r0, kc0)]) = bh0;
      *(int4*)(&BsH[gsw(64 + r0, kc0)]) = bh1;
      *(int4*)(&BsL[gsw(r0, kc0)]) = bl0;
      *(int4*)(&BsL[gsw(64 + r0, kc0)]) = bl1;
    } else {
      if (r0 < 64) {
        *(int4*)(&BsH[gsw(r0, kc0)]) = bh0;
        *(int4*)(&BsL[gsw(r0, kc0)]) = bl0;
      }
    }
    if (k0 + 32 < K) {
      ah0 = *(const int4*)(Aph + k0 + 32);
      ah1 = *(const int4*)(Aph + k0 + 32 + ah_s);
      al0 = *(const int4*)(Apl + k0 + 32);
      al1 = *(const int4*)(Apl + k0 + 32 + al_s);
      if constexpr (NT == 128) {
        bh0 = *(const int4*)(Wph + k0 + 32);
        bh1 = *(const int4*)(Wph + k0 + 32 + w_s);
        bl0 = *(const int4*)(Wpl + k0 + 32);
        bl1 = *(const int4*)(Wpl + k0 + 32 + w_s);
      } else if (r0 < 64) {
        bh0 = *(const int4*)(Wph + k0 + 32);
        bl0 = *(const int4*)(Wpl + k0 + 32);
      }
    }
    __syncthreads();
    bf16x8 afh[4], afl[4], bfh[NFR], bfl[NFR];
    #pragma unroll
    for (int i = 0; i < 4; i++) {
      afh[i] = *(const bf16x8*)(&AsH[gsw(wr * 64 + i * 16 + fr, kof)]);
      afl[i] = *(const bf16x8*)(&AsL[gsw(wr * 64 + i * 16 + fr, kof)]);
    }
    #pragma unroll
    for (int i = 0; i < NFR; i++) {
      bfh[i] = *(const bf16x8*)(&BsH[gsw(cb + i * 16 + fr, kof)]);
      bfl[i] = *(const bf16x8*)(&BsL[gsw(cb + i * 16 + fr, kof)]);
    }
    #pragma unroll
    for (int mi = 0; mi < 4; mi++)
      #pragma unroll
      for (int ni = 0; ni < NFR; ni++) {
        acc[mi][ni] = MFMA_BF16(afh[mi], bfh[ni], acc[mi][ni]);
        acc[mi][ni] = MFMA_BF16(afl[mi], bfh[ni], acc[mi][ni]);
        acc[mi][ni] = MFMA_BF16(afh[mi], bfl[ni], acc[mi][ni]);
      }
  }

  #pragma unroll
  for (int mi = 0; mi < 4; mi++) {
    #pragma unroll
    for (int ni = 0; ni < NFR; ni++) {
      int mrow = m0 + wr * 64 + mi * 16 + ((lane >> 4) << 2);
      int ocol = n0 + cb + ni * 16 + fr;
      if constexpr (EPI == 0) {          // fused QKV
        float bb = b0[ocol];
        if (ocol < 512) {                // Q or K: hi/lo row-major [xi,256]
          bf16* Dh = (ocol < 256) ? o0 : o2;
          bf16* Dl = (ocol < 256) ? o1 : o3;
          int oo = ocol & 255;
          #pragma unroll
          for (int r = 0; r < 4; r++) {
            float v = acc[mi][ni][r] + bb;
            unsigned short hi = f2bf(v);
            Dh[(size_t)(mrow + r) * 256 + oo] = hi;
            Dl[(size_t)(mrow + r) * 256 + oo] = f2bf(v - bf2f(hi));
          }
        } else {                         // V transposed hi/lo
          int c = ocol - 512;
          int dbi = mrow >> 11, nn = mrow & 2047;
          u16x4 ph, pl;
          #pragma unroll
          for (int r = 0; r < 4; r++) {
            float v = acc[mi][ni][r] + bb;
            unsigned short hi = f2bf(v);
            ph[r] = hi;
            pl[r] = f2bf(v - bf2f(hi));
          }
          *(u16x4*)(&o4[((size_t)dbi * 256 + c) * 2048 + nn]) = ph;
          *(u16x4*)(&o5[((size_t)dbi * 256 + c) * 2048 + nn]) = pl;
        }
      } else if constexpr (EPI == 2) {   // merge -> msg hi+lo
        float bb = b0[ocol];
        #pragma unroll
        for (int r = 0; r < 4; r++) {
          float v = acc[mi][ni][r] + bb;
          unsigned short hi = f2bf(v);
          o0[(size_t)(mrow + r) * 512 + 256 + ocol] = hi;
          o1[(size_t)(mrow + r) * 512 + 256 + ocol] = f2bf(v - bf2f(hi));
        }
      } else if constexpr (EPI == 3) {   // BN+ReLU hi+lo
        float ge = b0[ocol], be = b1[ocol];
        #pragma unroll
        for (int r = 0; r < 4; r++) {
          float v = fmaxf(ge * acc[mi][ni][r] + be, 0.f);
          unsigned short hi = f2bf(v);
          o0[(size_t)(mrow + r) * 512 + ocol] = hi;
          o1[(size_t)(mrow + r) * 512 + ocol] = f2bf(v - bf2f(hi));
        }
      } else {                           // EPI 4: residual
        float bb = b0[ocol];
        #pragma unroll
        for (int r = 0; r < 4; r++) {
          size_t ix = (size_t)(mrow + r) * 256 + ocol;
          float d = of[ix] + acc[mi][ni][r] + bb;
          of[ix] = d;
          unsigned short hi = f2bf(d);
          o0[(size_t)(mrow + r) * 512 + ocol] = hi;
          o1[(size_t)(mrow + r) * 512 + ocol] = f2bf(d - bf2f(hi));
        }
      }
    }
  }
}

// ---------------------------------------------------------------------------
// Flash attention, split-KV (2 halves of 1024), full split precision.
// Grid (16 n-blocks, 16 inst, 2 halves), 512 threads. QB=128, KB=64, dh=64.
// Scores arrive pre-scaled (exp2 direct). Emits unnormalized fp32 partial O
// and (m, l) per row/head/half; attn_combine merges.
// ---------------------------------------------------------------------------
DEVFN int swz(int row, int col) { return row * 64 + (col ^ ((row & 7) << 3)); }

__global__ __launch_bounds__(512) void attn3s(
    const bf16* __restrict__ Qh, const bf16* __restrict__ Ql,
    const bf16* __restrict__ Kh, const bf16* __restrict__ Kl,
    const bf16* __restrict__ Vth, const bf16* __restrict__ Vtl,
    float* __restrict__ Pacc, float* __restrict__ Ml, int cross)
{
  __shared__ bf16 Ksh[64 * 64];
  __shared__ bf16 Ksl[64 * 64];
  __shared__ bf16 Vsh[64 * 64];
  __shared__ bf16 Vsl[64 * 64];
  __shared__ bf16 Psh[8][16 * 64];
  __shared__ bf16 Psl[8][16 * 64];
  int tid = threadIdx.x, lane = tid & 63, w = tid >> 6;
  int inst = blockIdx.y;
  int half = blockIdx.z;
  int db = inst >> 2, hd = inst & 3;
  int dsc = db >> 1, bi = db & 1;
  int sdb = (cross ? (1 - dsc) : dsc) * 2 + bi;
  size_t xq = (size_t)db * 2048;
  size_t xs = (size_t)sdb * 2048 + half * 1024;
  int n0 = blockIdx.x * 128;

  int fr = lane & 15, kof = (lane >> 4) << 3;

  // Q fragments hi/lo: direct global -> registers
  bf16x8 aqh[2], aql[2];
  #pragma unroll
  for (int kf = 0; kf < 2; kf++) {
    size_t g = (xq + n0 + w * 16 + fr) * 256 + hd * 64 + kf * 32 + kof;
    aqh[kf] = *(const bf16x8*)(Qh + g);
    aql[kf] = *(const bf16x8*)(Ql + g);
  }

  f32x4 zero = {0.f, 0.f, 0.f, 0.f};
  f32x4 oacc[4];
  #pragma unroll
  for (int ni = 0; ni < 4; ni++) oacc[ni] = zero;
  float mrun[4], lrun[4];
  #pragma unroll
  for (int r = 0; r < 4; r++) { mrun[r] = -3.0e38f; lrun[r] = 0.f; }

  bf16x8 vone;
  #pragma unroll
  for (int i = 0; i < 8; i++) vone[i] = (short)0x3F80;  // bf16 1.0

  int srow = tid >> 3, skc = (tid & 7) << 3;
  const bf16* Kph = Kh + (xs + srow) * 256 + hd * 64 + skc;
  const bf16* Kpl = Kl + (xs + srow) * 256 + hd * 64 + skc;
  const bf16* Vph = Vth + ((size_t)sdb * 256 + hd * 64 + srow) * 2048 + half * 1024 + skc;
  const bf16* Vpl = Vtl + ((size_t)sdb * 256 + hd * 64 + srow) * 2048 + half * 1024 + skc;
  int4 ckh = *(const int4*)Kph;
  int4 ckl = *(const int4*)Kpl;
  int4 cvh = *(const int4*)Vph;
  int4 cvl = *(const int4*)Vpl;

  for (int t = 0; t < 16; t++) {
    __syncthreads();
    *(int4*)(&Ksh[swz(srow, skc)]) = ckh;
    *(int4*)(&Ksl[swz(srow, skc)]) = ckl;
    *(int4*)(&Vsh[swz(srow, skc)]) = cvh;
    *(int4*)(&Vsl[swz(srow, skc)]) = cvl;
    if (t + 1 < 16) {
      ckh = *(const int4*)(Kph + (size_t)(t + 1) * 64 * 256);
      ckl = *(const int4*)(Kpl + (size_t)(t + 1) * 64 * 256);
      cvh = *(const int4*)(Vph + (t + 1) * 64);
      cvl = *(const int4*)(Vpl + (t + 1) * 64);
    }
    __syncthreads();

    f32x4 sacc[4];
    #pragma unroll
    for (int ni = 0; ni < 4; ni++) sacc[ni] = zero;
    #pragma unroll
    for (int kf = 0; kf < 2; kf++) {
      #pragma unroll
      for (int ni = 0; ni < 4; ni++) {
        bf16x8 bkh = *(const bf16x8*)(&Ksh[swz(ni * 16 + fr, kf * 32 + kof)]);
        bf16x8 bkl = *(const bf16x8*)(&Ksl[swz(ni * 16 + fr, kf * 32 + kof)]);
        sacc[ni] = MFMA_BF16(aqh[kf], bkh, sacc[ni]);
        sacc[ni] = MFMA_BF16(aql[kf], bkh, sacc[ni]);
        sacc[ni] = MFMA_BF16(aqh[kf], bkl, sacc[ni]);
      }
    }

    float sc[4];
    #pragma unroll
    for (int r = 0; r < 4; r++) {
      float tm = fmaxf(fmaxf(sacc[0][r], sacc[1][r]), fmaxf(sacc[2][r], sacc[3][r]));
      tm = fmaxf(tm, __shfl_xor(tm, 1));
      tm = fmaxf(tm, __shfl_xor(tm, 2));
      tm = fmaxf(tm, __shfl_xor(tm, 4));
      tm = fmaxf(tm, __shfl_xor(tm, 8));
      float mn = fmaxf(mrun[r], tm);
      sc[r] = exp2f(mrun[r] - mn);
      mrun[r] = mn;
      #pragma unroll
      for (int ni = 0; ni < 4; ni++)
        sacc[ni][r] = exp2f(sacc[ni][r] - mn);
      #pragma unroll
      for (int ni = 0; ni < 4; ni++) oacc[ni][r] *= sc[r];
    }

    bf16* Pwh = &Psh[w][0];
    bf16* Pwl = &Psl[w][0];
    #pragma unroll
    for (int ni = 0; ni < 4; ni++) {
      int col = ni * 16 + fr;
      #pragma unroll
      for (int r = 0; r < 4; r++) {
        int row = ((lane >> 4) << 2) + r;
        float pv = sacc[ni][r];
        unsigned short hi = f2bf(pv);
        Pwh[swz(row, col)] = hi;
        Pwl[swz(row, col)] = f2bf(pv - bf2f(hi));
      }
    }

    // PV (3-term) + row-sum via ones-MFMA
    f32x4 racc = zero;
    #pragma unroll
    for (int kf = 0; kf < 2; kf++) {
      bf16x8 pah = *(const bf16x8*)(&Pwh[swz(fr, kf * 32 + kof)]);
      bf16x8 pal = *(const bf16x8*)(&Pwl[swz(fr, kf * 32 + kof)]);
      #pragma unroll
      for (int ni = 0; ni < 4; ni++) {
        bf16x8 bvh = *(const bf16x8*)(&Vsh[swz(ni * 16 + fr, kf * 32 + kof)]);
        bf16x8 bvl = *(const bf16x8*)(&Vsl[swz(ni * 16 + fr, kf * 32 + kof)]);
        oacc[ni] = MFMA_BF16(pah, bvh, oacc[ni]);
        oacc[ni] = MFMA_BF16(pal, bvh, oacc[ni]);
        oacc[ni] = MFMA_BF16(pah, bvl, oacc[ni]);
      }
      racc = MFMA_BF16(pah, vone, racc);
      racc = MFMA_BF16(pal, vone, racc);
    }
    #pragma unroll
    for (int r = 0; r < 4; r++)
      lrun[r] = lrun[r] * sc[r] + racc[r];
  }

  // store unnormalized partial O (fp32) + per-row (m, l)
  float* Pb = Pacc + (size_t)half * 8192 * 256;
  #pragma unroll
  for (int r = 0; r < 4; r++) {
    int nrow = n0 + w * 16 + ((lane >> 4) << 2) + r;
    size_t row = xq + nrow;
    #pragma unroll
    for (int ni = 0; ni < 4; ni++)
      Pb[row * 256 + hd * 64 + ni * 16 + fr] = oacc[ni][r];
    if (fr == 0) {
      float* mp = Ml + ((row * 4 + hd) << 2) + half * 2;
      mp[0] = mrun[r];
      mp[1] = lrun[r];
    }
  }
}

// ---------------------------------------------------------------------------
// Combine the two KV halves: O = (Pa*wa + Pb*wb) / (la*wa + lb*wb), hi/lo out.
// Grid 2048 blocks x 256 thr; each wave handles one row (4 cols/lane).
// ---------------------------------------------------------------------------
__global__ __launch_bounds__(256) void attn_combine(
    const float* __restrict__ Pacc, const float* __restrict__ Ml,
    bf16* __restrict__ Oh, bf16* __restrict__ Ol)
{
  int tid = threadIdx.x, lane = tid & 63, w = tid >> 6;
  size_t row = (size_t)blockIdx.x * 4 + w;
  int hd = lane >> 4;
  int c0 = lane * 4;
  const float* mp = Ml + ((row * 4 + hd) << 2);
  float ma = mp[0], la = mp[1], mb = mp[2], lb = mp[3];
  float m = fmaxf(ma, mb);
  float wa = exp2f(ma - m), wb = exp2f(mb - m);
  float inv = 1.0f / (la * wa + lb * wb);
  wa *= inv; wb *= inv;
  f32x4 pa = *(const f32x4*)(Pacc + row * 256 + c0);
  f32x4 pb = *(const f32x4*)(Pacc + (size_t)8192 * 256 + row * 256 + c0);
  u16x4 vh, vl;
  #pragma unroll
  for (int r = 0; r < 4; r++) {
    float v = pa[r] * wa + pb[r] * wb;
    unsigned short hi = f2bf(v);
    vh[r] = hi;
    vl[r] = f2bf(v - bf2f(hi));
  }
  *(u16x4*)(Oh + row * 256 + c0) = vh;
  *(u16x4*)(Ol + row * 256 + c0) = vl;
}

// ---------------------------------------------------------------------------
extern "C" void kernel_launch(void* const* d_in, const int* in_sizes, int n_in,
                              void* d_out, int out_size, void* d_ws, size_t ws_size,
                              hipStream_t stream)
{
  (void)in_sizes; (void)n_in; (void)out_size; (void)ws_size;
  const float* desc0 = (const float*)d_in[0];
  const float* desc1 = (const float*)d_in[1];
  const float* Wq = (const float*)d_in[2];
  const float* bq = (const float*)d_in[3];
  const float* Wk = (const float*)d_in[4];
  const float* bk = (const float*)d_in[5];
  const float* Wv = (const float*)d_in[6];
  const float* bv = (const float*)d_in[7];
  const float* Wm = (const float*)d_in[8];
  const float* bm = (const float*)d_in[9];
  const float* W1 = (const float*)d_in[10];
  const float* b1 = (const float*)d_in[11];
  const float* gm = (const float*)d_in[12];
  const float* bt = (const float*)d_in[13];
  const float* W2 = (const float*)d_in[14];
  const float* b2 = (const float*)d_in[15];
  float* out = (float*)d_out;

  char* ws = (char*)d_ws;
  bf16*  Wbf  = (bf16*)(ws + 0);            //  31,457,280
  float* bias = (float*)(ws + 31457280);    //     110,592
  float* Dm   = (float*)(ws + 31567872);    //  16,777,216  fp32 master [xi,256]
  bf16*  Hin  = (bf16*)(ws + 48345088);     //  16,777,216  [xi,512] = xh | msg_h
  bf16*  XMl  = (bf16*)(ws + 65122304);     //  16,777,216  [xi,512] = xl | msg_l
  bf16*  Qh   = (bf16*)(ws + 81899520);     //   8,388,608
  bf16*  Ql   = (bf16*)(ws + 90288128);     //   8,388,608
  bf16*  Kh   = (bf16*)(ws + 98676736);     //   8,388,608
  bf16*  Kl   = (bf16*)(ws + 107065344);    //   8,388,608
  bf16*  Vth  = (bf16*)(ws + 115453952);    //   8,388,608  [db,256,2048]
  bf16*  Vtl  = (bf16*)(ws + 123842560);    //   8,388,608
  bf16*  Oh   = (bf16*)(ws + 132231168);    //   8,388,608
  bf16*  Ol   = (bf16*)(ws + 140619776);    //   8,388,608
  float* Pacc = (float*)(ws + 149008384);   //  16,777,216  [2][8192][256] fp32
  float* Ml   = (float*)(ws + 165785600);   //     524,288  [8192][4][4]
  // end: 166,309,888
  bf16*  Hbh  = Qh;                         // alias Qh+Ql (disjoint in time)
  bf16*  Hbl  = Kh;                         // alias Kh+Kl

  prep_weights<<<dim3(5130, 12), 256, 0, stream>>>(Wq, bq, Wk, bk, Wv, bv, Wm, bm,
                                                   W1, b1, gm, bt, W2, b2, Wbf, bias);
  transpose_in<<<dim3(64, 8, 4), dim3(32, 8), 0, stream>>>(desc0, desc1, Dm, Hin, XMl);

  for (int l = 0; l < NL; l++) {
    const bf16* wl = Wbf + (size_t)l * 1310720;
    const float* bl = bias + l * 2304;
    int cross = l & 1;
    // fused QKV (Q pre-scaled by log2e/8)
    gemm3<0, 128><<<dim3(64, 6), 256, 0, stream>>>(Hin, 512, XMl, 512,
        wl, wl + 196608, 256, bl, nullptr,
        Qh, Ql, Kh, Kl, Vth, Vtl, nullptr);
    // split-KV attention + combine
    attn3s<<<dim3(16, 16, 2), 512, 0, stream>>>(Qh, Ql, Kh, Kl, Vth, Vtl,
                                                Pacc, Ml, cross);
    attn_combine<<<2048, 256, 0, stream>>>(Pacc, Ml, Oh, Ol);
    // merge: msg = O·Wm^T
    gemm3<2, 64><<<dim3(64, 4), 256, 0, stream>>>(Oh, 256, Ol, 256,
        wl + 393216, wl + 458752, 256, bl + 768, nullptr,
        Hin, XMl, nullptr, nullptr, nullptr, nullptr, nullptr);
    // MLP1 + BN + ReLU
    gemm3<3, 128><<<dim3(64, 4), 256, 0, stream>>>(Hin, 512, XMl, 512,
        wl + 524288, wl + 786432, 512, bl + 1024, bl + 1536,
        Hbh, Hbl, nullptr, nullptr, nullptr, nullptr, nullptr);
    // MLP2 + residual
    gemm3<4, 64><<<dim3(64, 4), 256, 0, stream>>>(Hbh, 512, Hbl, 512,
        wl + 1048576, wl + 1179648, 512, bl + 2048, nullptr,
        Hin, XMl, nullptr, nullptr, nullptr, nullptr, Dm);
  }
  transpose_out<<<dim3(64, 8, 4), dim3(32, 8), 0, stream>>>(Dm, out);
}

// Round 7
// 1923.085 us; speedup vs baseline: 1.2626x; 1.0181x over previous
//
#include <hip/hip_runtime.h>

typedef unsigned short bf16;
typedef __attribute__((ext_vector_type(8))) short bf16x8;
typedef __attribute__((ext_vector_type(4))) float f32x4;
typedef unsigned short u16x4 __attribute__((ext_vector_type(4)));

#define DEVFN static __device__ __forceinline__

#define NL 12

DEVFN unsigned short f2bf(float f) {
  union { float f; unsigned u; } v; v.f = f;
  unsigned u = v.u;
  unsigned r = (u + 0x7fffu + ((u >> 16) & 1u)) >> 16;  // RNE
  return (unsigned short)r;
}
DEVFN float bf2f(unsigned short h) {
  union { unsigned u; float f; } v; v.u = ((unsigned)h) << 16; return v.f;
}
// truncation hi/lo split: 4 ALU ops, pair error ~2^-18 (hi biased, lo captures)
DEVFN void tsplit(float v, unsigned short& h, unsigned short& l) {
  union { float f; unsigned u; } a; a.f = v;
  h = (unsigned short)(a.u >> 16);
  union { float f; unsigned u; } b; b.u = a.u & 0xffff0000u;
  union { float f; unsigned u; } c; c.f = v - b.f;
  l = (unsigned short)(c.u >> 16);
}
// async global->LDS, 16B per lane; dest = wave-uniform base + lane*16
DEVFN void gll16(const bf16* g, bf16* l) {
  __builtin_amdgcn_global_load_lds(
      (const __attribute__((address_space(1))) unsigned int*)g,
      (__attribute__((address_space(3))) unsigned int*)l, 16, 0, 0);
}

#define MFMA_BF16(a, b, c) __builtin_amdgcn_mfma_f32_16x16x32_bf16((a), (b), (c), 0, 0, 0)

// ---------------------------------------------------------------------------
// Weight prep: hi/lo bf16 split of every weight (RNE, one-time). Wq/bq folded
// with Cs = log2(e)/8. Layout per layer (1310720 bf16):
//   [0,196608) Wqkv hi | [196608,393216) Wqkv lo | [393216,458752) Wm hi
//   [458752,524288) Wm lo | [524288,786432) W1 hi | [786432,1048576) W1 lo
//   [1048576,1179648) W2 hi | [1179648,1310720) W2 lo
// f32 bias block (2304): bqkv[768] | bm[256] | geff[512] | beff[512] | b2[256]
// ---------------------------------------------------------------------------
__global__ void prep_weights(const float* __restrict__ Wq, const float* __restrict__ bq,
                             const float* __restrict__ Wk, const float* __restrict__ bk,
                             const float* __restrict__ Wv, const float* __restrict__ bv,
                             const float* __restrict__ Wm, const float* __restrict__ bm,
                             const float* __restrict__ W1, const float* __restrict__ b1,
                             const float* __restrict__ gm, const float* __restrict__ bt,
                             const float* __restrict__ W2, const float* __restrict__ b2,
                             bf16* __restrict__ Wbf, float* __restrict__ bias)
{
  int l = blockIdx.y;
  bf16* wl = Wbf + (size_t)l * 1310720;
  float* bl = bias + l * 2304;
  int idx = blockIdx.x * blockDim.x + threadIdx.x;
  if (idx >= 1310720 + 2304) return;
  const float INV = 1.0f / sqrtf(1.0f + 1e-5f);
  const float Cs = 0.18033688011112042f;  // log2(e)/8

  float w = 0.f;
  int lo = 0;
  if (idx < 393216) {                         // Wqkv
    int j = idx; lo = (j >= 196608); j -= lo * 196608;
    int t = j >> 16;
    int p = (j >> 8) & 255;
    int k = j & 255;
    int c = ((p & 63) << 2) | (p >> 6);       // p = h*64+i -> c = i*4+h
    const float* W = (t == 0) ? Wq : (t == 1) ? Wk : Wv;
    w = W[(size_t)l * 65536 + c * 256 + k];
    if (t == 0) w *= Cs;
  } else if (idx < 524288) {                  // Wm (cols permuted)
    int j = idx - 393216; lo = (j >= 65536); j -= lo * 65536;
    int o = j >> 8, p = j & 255;
    int c = ((p & 63) << 2) | (p >> 6);
    w = Wm[(size_t)l * 65536 + o * 256 + c];
  } else if (idx < 1048576) {                 // W1
    int j = idx - 524288; lo = (j >= 262144); j &= 262143;
    w = W1[(size_t)l * 262144 + j];
  } else if (idx < 1310720) {                 // W2
    int j = idx - 1048576; lo = (j >= 131072); j &= 131071;
    w = W2[(size_t)l * 131072 + j];
  } else {
    int j = idx - 1310720;
    if (j < 768) {
      int t = j >> 8, p = j & 255;
      int c = ((p & 63) << 2) | (p >> 6);
      const float* bsrc = (t == 0) ? bq : (t == 1) ? bk : bv;
      bl[j] = bsrc[l * 256 + c] * ((t == 0) ? Cs : 1.0f);
    } else if (j < 1024) {
      bl[j] = bm[l * 256 + (j - 768)];
    } else if (j < 1536) {
      bl[j] = gm[l * 512 + (j - 1024)] * INV;
    } else if (j < 2048) {
      int o = j - 1536;
      bl[j] = gm[l * 512 + o] * INV * b1[l * 512 + o] + bt[l * 512 + o];
    } else {
      bl[j] = b2[l * 256 + (j - 2048)];
    }
    return;
  }
  unsigned short hi = f2bf(w);
  wl[idx] = lo ? f2bf(w - bf2f(hi)) : hi;
}

// ---------------------------------------------------------------------------
// Input transpose: desc [b,d,n] fp32 -> Dm [xi,256] fp32; Hin[:,0:256]=x hi;
// XMl[:,0:256]=x lo (both lda 512).
// ---------------------------------------------------------------------------
__global__ void transpose_in(const float* __restrict__ s0, const float* __restrict__ s1,
                             float* __restrict__ Dm, bf16* __restrict__ Hin,
                             bf16* __restrict__ XMl)
{
  __shared__ float t[32][33];
  int db = blockIdx.z;
  int dsc = db >> 1, bi = db & 1;
  const float* src = dsc ? s1 : s0;
  int n0 = blockIdx.x * 32, d0 = blockIdx.y * 32;
  int tx = threadIdx.x, ty = threadIdx.y;
  #pragma unroll
  for (int i = 0; i < 32; i += 8)
    t[ty + i][tx] = src[(size_t)(bi * 256 + d0 + ty + i) * 2048 + n0 + tx];
  __syncthreads();
  #pragma unroll
  for (int i = 0; i < 32; i += 8) {
    size_t xi = (size_t)db * 2048 + n0 + ty + i;
    float v = t[tx][ty + i];
    Dm[xi * 256 + d0 + tx] = v;
    unsigned short hi, lo;
    tsplit(v, hi, lo);
    Hin[xi * 512 + d0 + tx] = hi;
    XMl[xi * 512 + d0 + tx] = lo;
  }
}

__global__ void transpose_out(const float* __restrict__ Dm, float* __restrict__ out)
{
  __shared__ float t[32][33];
  int db = blockIdx.z;
  int n0 = blockIdx.x * 32, d0 = blockIdx.y * 32;
  int tx = threadIdx.x, ty = threadIdx.y;
  #pragma unroll
  for (int i = 0; i < 32; i += 8)
    t[ty + i][tx] = Dm[((size_t)db * 2048 + n0 + ty + i) * 256 + d0 + tx];
  __syncthreads();
  #pragma unroll
  for (int i = 0; i < 32; i += 8)
    out[(size_t)(db * 256 + d0 + ty + i) * 2048 + n0 + tx] = t[tx][ty + i];
}

// ---------------------------------------------------------------------------
// 3-term split GEMM with global_load_lds staging.
// LDS is gsw-swizzled via pre-swizzled SOURCE addresses (linear dest).
// Tile 128xNT, BK=32, 4 waves (2x2). Reads use gsw() exactly as before.
// ---------------------------------------------------------------------------
DEVFN int gsw(int row, int col) { return row * 32 + (col ^ ((row & 3) << 3)); }

template<int EPI, int NT>
__global__ __launch_bounds__(256, 3) void gemm3(
    const bf16* __restrict__ Ah, int lda,
    const bf16* __restrict__ Al, int ldal,
    const bf16* __restrict__ Wh, const bf16* __restrict__ Wl, int K,
    const float* __restrict__ b0, const float* __restrict__ b1,
    bf16* __restrict__ o0, bf16* __restrict__ o1,
    bf16* __restrict__ o2, bf16* __restrict__ o3,
    bf16* __restrict__ o4, bf16* __restrict__ o5,
    float* __restrict__ of)
{
  constexpr int NFR = NT / 32;
  __shared__ bf16 AsH[128 * 32];
  __shared__ bf16 AsL[128 * 32];
  __shared__ bf16 BsH[NT * 32];
  __shared__ bf16 BsL[NT * 32];
  int tid = threadIdx.x, lane = tid & 63, wid = tid >> 6;
  int wr = wid >> 1, wc = wid & 1;
  int m0 = blockIdx.x * 128, n0 = blockIdx.y * NT;

  // staging source (pre-swizzled): lane -> row wid*16 + (lane>>2), granule (lane&3)^((lane>>2)&3)
  int lrow = lane >> 2;
  int g4 = ((lane & 3) ^ (lrow & 3)) << 3;    // element offset of 16B granule
  const bf16* A0h = Ah + (size_t)(m0 + wid * 16 + lrow) * lda + g4;
  const bf16* A0l = Al + (size_t)(m0 + wid * 16 + lrow) * ldal + g4;
  const bf16* B0h = Wh + (size_t)(n0 + wid * 16 + lrow) * K + g4;
  const bf16* B0l = Wl + (size_t)(n0 + wid * 16 + lrow) * K + g4;
  size_t a64h = (size_t)64 * lda, a64l = (size_t)64 * ldal, b64 = (size_t)64 * K;
  bf16* LAh = AsH + wid * 512;
  bf16* LAl = AsL + wid * 512;
  bf16* LBh = BsH + wid * 512;
  bf16* LBl = BsL + wid * 512;

  f32x4 zero = {0.f, 0.f, 0.f, 0.f};
  f32x4 acc[4][NFR];
  #pragma unroll
  for (int i = 0; i < 4; i++)
    #pragma unroll
    for (int j = 0; j < NFR; j++) acc[i][j] = zero;

  int fr = lane & 15, kof = (lane >> 4) << 3;
  int cb = wc * (NT / 2);
  for (int k0 = 0; k0 < K; k0 += 32) {
    __syncthreads();                       // prev tile fully consumed
    gll16(A0h + k0, LAh);
    gll16(A0h + a64h + k0, LAh + 2048);
    gll16(A0l + k0, LAl);
    gll16(A0l + a64l + k0, LAl + 2048);
    gll16(B0h + k0, LBh);
    gll16(B0l + k0, LBl);
    if constexpr (NT == 128) {
      gll16(B0h + b64 + k0, LBh + 2048);
      gll16(B0l + b64 + k0, LBl + 2048);
    }
    __syncthreads();                       // drains vmcnt -> tiles resident
    bf16x8 afh[4], afl[4], bfh[NFR], bfl[NFR];
    #pragma unroll
    for (int i = 0; i < 4; i++) {
      afh[i] = *(const bf16x8*)(&AsH[gsw(wr * 64 + i * 16 + fr, kof)]);
      afl[i] = *(const bf16x8*)(&AsL[gsw(wr * 64 + i * 16 + fr, kof)]);
    }
    #pragma unroll
    for (int i = 0; i < NFR; i++) {
      bfh[i] = *(const bf16x8*)(&BsH[gsw(cb + i * 16 + fr, kof)]);
      bfl[i] = *(const bf16x8*)(&BsL[gsw(cb + i * 16 + fr, kof)]);
    }
    #pragma unroll
    for (int mi = 0; mi < 4; mi++)
      #pragma unroll
      for (int ni = 0; ni < NFR; ni++) {
        acc[mi][ni] = MFMA_BF16(afh[mi], bfh[ni], acc[mi][ni]);
        acc[mi][ni] = MFMA_BF16(afl[mi], bfh[ni], acc[mi][ni]);
        acc[mi][ni] = MFMA_BF16(afh[mi], bfl[ni], acc[mi][ni]);
      }
  }

  #pragma unroll
  for (int mi = 0; mi < 4; mi++) {
    #pragma unroll
    for (int ni = 0; ni < NFR; ni++) {
      int mrow = m0 + wr * 64 + mi * 16 + ((lane >> 4) << 2);
      int ocol = n0 + cb + ni * 16 + fr;
      if constexpr (EPI == 0) {          // fused QKV
        float bb = b0[ocol];
        if (ocol < 512) {                // Q or K hi/lo [xi,256]
          bf16* Dh = (ocol < 256) ? o0 : o2;
          bf16* Dl = (ocol < 256) ? o1 : o3;
          int oo = ocol & 255;
          #pragma unroll
          for (int r = 0; r < 4; r++) {
            unsigned short hi, lo;
            tsplit(acc[mi][ni][r] + bb, hi, lo);
            Dh[(size_t)(mrow + r) * 256 + oo] = hi;
            Dl[(size_t)(mrow + r) * 256 + oo] = lo;
          }
        } else {                         // V transposed hi/lo
          int c = ocol - 512;
          int dbi = mrow >> 11, nn = mrow & 2047;
          u16x4 ph, pl;
          #pragma unroll
          for (int r = 0; r < 4; r++) {
            unsigned short hi, lo;
            tsplit(acc[mi][ni][r] + bb, hi, lo);
            ph[r] = hi; pl[r] = lo;
          }
          *(u16x4*)(&o4[((size_t)dbi * 256 + c) * 2048 + nn]) = ph;
          *(u16x4*)(&o5[((size_t)dbi * 256 + c) * 2048 + nn]) = pl;
        }
      } else if constexpr (EPI == 2) {   // merge -> msg hi+lo
        float bb = b0[ocol];
        #pragma unroll
        for (int r = 0; r < 4; r++) {
          unsigned short hi, lo;
          tsplit(acc[mi][ni][r] + bb, hi, lo);
          o0[(size_t)(mrow + r) * 512 + 256 + ocol] = hi;
          o1[(size_t)(mrow + r) * 512 + 256 + ocol] = lo;
        }
      } else if constexpr (EPI == 3) {   // BN+ReLU hi+lo
        float ge = b0[ocol], be = b1[ocol];
        #pragma unroll
        for (int r = 0; r < 4; r++) {
          unsigned short hi, lo;
          tsplit(fmaxf(ge * acc[mi][ni][r] + be, 0.f), hi, lo);
          o0[(size_t)(mrow + r) * 512 + ocol] = hi;
          o1[(size_t)(mrow + r) * 512 + ocol] = lo;
        }
      } else {                           // EPI 4: residual
        float bb = b0[ocol];
        #pragma unroll
        for (int r = 0; r < 4; r++) {
          size_t ix = (size_t)(mrow + r) * 256 + ocol;
          float d = of[ix] + acc[mi][ni][r] + bb;
          of[ix] = d;
          unsigned short hi, lo;
          tsplit(d, hi, lo);
          o0[(size_t)(mrow + r) * 512 + ocol] = hi;
          o1[(size_t)(mrow + r) * 512 + ocol] = lo;
        }
      }
    }
  }
}

// ---------------------------------------------------------------------------
// Flash attention, split-KV (2 halves), 3-term QK^T and PV.
// Grid (16, 16, 2) = 512 blocks = 2/CU; launch_bounds(512,4) caps regs at 128
// so both blocks are resident. K/V staged via global_load_lds (pre-swizzled
// source, linear dest); P split via truncation.
// ---------------------------------------------------------------------------
DEVFN int swz(int row, int col) { return row * 64 + (col ^ ((row & 7) << 3)); }

__global__ __launch_bounds__(512, 4) void attn3s(
    const bf16* __restrict__ Qh, const bf16* __restrict__ Ql,
    const bf16* __restrict__ Kh, const bf16* __restrict__ Kl,
    const bf16* __restrict__ Vth, const bf16* __restrict__ Vtl,
    float* __restrict__ Pacc, float* __restrict__ Ml, int cross)
{
  __shared__ bf16 Ksh[64 * 64];
  __shared__ bf16 Ksl[64 * 64];
  __shared__ bf16 Vsh[64 * 64];
  __shared__ bf16 Vsl[64 * 64];
  __shared__ bf16 Psh[8][1024];
  __shared__ bf16 Psl[8][1024];
  int tid = threadIdx.x, lane = tid & 63, w = tid >> 6;
  int inst = blockIdx.y;
  int half = blockIdx.z;
  int db = inst >> 2, hd = inst & 3;
  int dsc = db >> 1, bi = db & 1;
  int sdb = (cross ? (1 - dsc) : dsc) * 2 + bi;
  size_t xq = (size_t)db * 2048;
  size_t xs = (size_t)sdb * 2048 + half * 1024;
  int n0 = blockIdx.x * 128;

  int fr = lane & 15, kof = (lane >> 4) << 3;

  // Q fragments hi/lo: direct global -> registers
  bf16x8 aqh[2], aql[2];
  #pragma unroll
  for (int kf = 0; kf < 2; kf++) {
    size_t g = (xq + n0 + w * 16 + fr) * 256 + hd * 64 + kf * 32 + kof;
    aqh[kf] = *(const bf16x8*)(Qh + g);
    aql[kf] = *(const bf16x8*)(Ql + g);
  }

  f32x4 zero = {0.f, 0.f, 0.f, 0.f};
  f32x4 oacc[4];
  #pragma unroll
  for (int ni = 0; ni < 4; ni++) oacc[ni] = zero;
  float mrun[4], lrun[4];
  #pragma unroll
  for (int r = 0; r < 4; r++) { mrun[r] = -3.0e38f; lrun[r] = 0.f; }

  bf16x8 vone;
  #pragma unroll
  for (int i = 0; i < 8; i++) vone[i] = (short)0x3F80;  // bf16 1.0

  // staging sources (pre-swizzled): lane -> row w*8 + (lane>>3),
  // granule (lane&7) ^ ((lane>>3)&7)
  int lrow = lane >> 3;
  int g8 = ((lane & 7) ^ (lrow & 7)) << 3;
  int krow = w * 8 + lrow;
  const bf16* Ksrc_h = Kh + (xs + krow) * 256 + hd * 64 + g8;
  const bf16* Ksrc_l = Kl + (xs + krow) * 256 + hd * 64 + g8;
  const bf16* Vsrc_h = Vth + ((size_t)sdb * 256 + hd * 64 + krow) * 2048 + half * 1024 + g8;
  const bf16* Vsrc_l = Vtl + ((size_t)sdb * 256 + hd * 64 + krow) * 2048 + half * 1024 + g8;
  bf16* LKh = Ksh + w * 512;
  bf16* LKl = Ksl + w * 512;
  bf16* LVh = Vsh + w * 512;
  bf16* LVl = Vsl + w * 512;

  for (int t = 0; t < 16; t++) {
    __syncthreads();                       // prev tile consumed by all waves
    gll16(Ksrc_h + (size_t)t * 16384, LKh);
    gll16(Ksrc_l + (size_t)t * 16384, LKl);
    gll16(Vsrc_h + t * 64, LVh);
    gll16(Vsrc_l + t * 64, LVl);
    __syncthreads();                       // drains vmcnt -> tiles resident

    f32x4 sacc[4];
    #pragma unroll
    for (int ni = 0; ni < 4; ni++) sacc[ni] = zero;
    #pragma unroll
    for (int kf = 0; kf < 2; kf++) {
      #pragma unroll
      for (int ni = 0; ni < 4; ni++) {
        bf16x8 bkh = *(const bf16x8*)(&Ksh[swz(ni * 16 + fr, kf * 32 + kof)]);
        bf16x8 bkl = *(const bf16x8*)(&Ksl[swz(ni * 16 + fr, kf * 32 + kof)]);
        sacc[ni] = MFMA_BF16(aqh[kf], bkh, sacc[ni]);
        sacc[ni] = MFMA_BF16(aql[kf], bkh, sacc[ni]);
        sacc[ni] = MFMA_BF16(aqh[kf], bkl, sacc[ni]);
      }
    }

    float sc[4];
    #pragma unroll
    for (int r = 0; r < 4; r++) {
      float tm = fmaxf(fmaxf(sacc[0][r], sacc[1][r]), fmaxf(sacc[2][r], sacc[3][r]));
      tm = fmaxf(tm, __shfl_xor(tm, 1));
      tm = fmaxf(tm, __shfl_xor(tm, 2));
      tm = fmaxf(tm, __shfl_xor(tm, 4));
      tm = fmaxf(tm, __shfl_xor(tm, 8));
      float mn = fmaxf(mrun[r], tm);
      sc[r] = exp2f(mrun[r] - mn);
      mrun[r] = mn;
      #pragma unroll
      for (int ni = 0; ni < 4; ni++)
        sacc[ni][r] = exp2f(sacc[ni][r] - mn);
      #pragma unroll
      for (int ni = 0; ni < 4; ni++) oacc[ni][r] *= sc[r];
    }

    bf16* Pwh = &Psh[w][0];
    bf16* Pwl = &Psl[w][0];
    #pragma unroll
    for (int ni = 0; ni < 4; ni++) {
      int col = ni * 16 + fr;
      #pragma unroll
      for (int r = 0; r < 4; r++) {
        int row = ((lane >> 4) << 2) + r;
        unsigned short hi, lo;
        tsplit(sacc[ni][r], hi, lo);
        Pwh[swz(row, col)] = hi;
        Pwl[swz(row, col)] = lo;
      }
    }

    // PV (3-term) + row-sum via ones-MFMA (P written/read by the SAME wave)
    f32x4 racc = zero;
    #pragma unroll
    for (int kf = 0; kf < 2; kf++) {
      bf16x8 pah = *(const bf16x8*)(&Pwh[swz(fr, kf * 32 + kof)]);
      bf16x8 pal = *(const bf16x8*)(&Pwl[swz(fr, kf * 32 + kof)]);
      #pragma unroll
      for (int ni = 0; ni < 4; ni++) {
        bf16x8 bvh = *(const bf16x8*)(&Vsh[swz(ni * 16 + fr, kf * 32 + kof)]);
        bf16x8 bvl = *(const bf16x8*)(&Vsl[swz(ni * 16 + fr, kf * 32 + kof)]);
        oacc[ni] = MFMA_BF16(pah, bvh, oacc[ni]);
        oacc[ni] = MFMA_BF16(pal, bvh, oacc[ni]);
        oacc[ni] = MFMA_BF16(pah, bvl, oacc[ni]);
      }
      racc = MFMA_BF16(pah, vone, racc);
      racc = MFMA_BF16(pal, vone, racc);
    }
    #pragma unroll
    for (int r = 0; r < 4; r++)
      lrun[r] = lrun[r] * sc[r] + racc[r];
  }

  // store unnormalized partial O (fp32) + per-row (m, l)
  float* Pb = Pacc + (size_t)half * 8192 * 256;
  #pragma unroll
  for (int r = 0; r < 4; r++) {
    int nrow = n0 + w * 16 + ((lane >> 4) << 2) + r;
    size_t row = xq + nrow;
    #pragma unroll
    for (int ni = 0; ni < 4; ni++)
      Pb[row * 256 + hd * 64 + ni * 16 + fr] = oacc[ni][r];
    if (fr == 0) {
      float* mp = Ml + ((row * 4 + hd) << 2) + half * 2;
      mp[0] = mrun[r];
      mp[1] = lrun[r];
    }
  }
}

// ---------------------------------------------------------------------------
// Combine the two KV halves: O = (Pa*wa + Pb*wb) / (la*wa + lb*wb), hi/lo out.
// ---------------------------------------------------------------------------
__global__ __launch_bounds__(256) void attn_combine(
    const float* __restrict__ Pacc, const float* __restrict__ Ml,
    bf16* __restrict__ Oh, bf16* __restrict__ Ol)
{
  int tid = threadIdx.x, lane = tid & 63, w = tid >> 6;
  size_t row = (size_t)blockIdx.x * 4 + w;
  int hd = lane >> 4;
  int c0 = lane * 4;
  const float* mp = Ml + ((row * 4 + hd) << 2);
  float ma = mp[0], la = mp[1], mb = mp[2], lb = mp[3];
  float m = fmaxf(ma, mb);
  float wa = exp2f(ma - m), wb = exp2f(mb - m);
  float inv = 1.0f / (la * wa + lb * wb);
  wa *= inv; wb *= inv;
  f32x4 pa = *(const f32x4*)(Pacc + row * 256 + c0);
  f32x4 pb = *(const f32x4*)(Pacc + (size_t)8192 * 256 + row * 256 + c0);
  u16x4 vh, vl;
  #pragma unroll
  for (int r = 0; r < 4; r++) {
    unsigned short hi, lo;
    tsplit(pa[r] * wa + pb[r] * wb, hi, lo);
    vh[r] = hi; vl[r] = lo;
  }
  *(u16x4*)(Oh + row * 256 + c0) = vh;
  *(u16x4*)(Ol + row * 256 + c0) = vl;
}

// ---------------------------------------------------------------------------
extern "C" void kernel_launch(void* const* d_in, const int* in_sizes, int n_in,
                              void* d_out, int out_size, void* d_ws, size_t ws_size,
                              hipStream_t stream)
{
  (void)in_sizes; (void)n_in; (void)out_size; (void)ws_size;
  const float* desc0 = (const float*)d_in[0];
  const float* desc1 = (const float*)d_in[1];
  const float* Wq = (const float*)d_in[2];
  const float* bq = (const float*)d_in[3];
  const float* Wk = (const float*)d_in[4];
  const float* bk = (const float*)d_in[5];
  const float* Wv = (const float*)d_in[6];
  const float* bv = (const float*)d_in[7];
  const float* Wm = (const float*)d_in[8];
  const float* bm = (const float*)d_in[9];
  const float* W1 = (const float*)d_in[10];
  const float* b1 = (const float*)d_in[11];
  const float* gm = (const float*)d_in[12];
  const float* bt = (const float*)d_in[13];
  const float* W2 = (const float*)d_in[14];
  const float* b2 = (const float*)d_in[15];
  float* out = (float*)d_out;

  char* ws = (char*)d_ws;
  bf16*  Wbf  = (bf16*)(ws + 0);            //  31,457,280
  float* bias = (float*)(ws + 31457280);    //     110,592
  float* Dm   = (float*)(ws + 31567872);    //  16,777,216  fp32 master [xi,256]
  bf16*  Hin  = (bf16*)(ws + 48345088);     //  16,777,216  [xi,512] = xh | msg_h
  bf16*  XMl  = (bf16*)(ws + 65122304);     //  16,777,216  [xi,512] = xl | msg_l
  bf16*  Qh   = (bf16*)(ws + 81899520);     //   8,388,608
  bf16*  Ql   = (bf16*)(ws + 90288128);     //   8,388,608
  bf16*  Kh   = (bf16*)(ws + 98676736);     //   8,388,608
  bf16*  Kl   = (bf16*)(ws + 107065344);    //   8,388,608
  bf16*  Vth  = (bf16*)(ws + 115453952);    //   8,388,608  [db,256,2048]
  bf16*  Vtl  = (bf16*)(ws + 123842560);    //   8,388,608
  bf16*  Oh   = (bf16*)(ws + 132231168);    //   8,388,608
  bf16*  Ol   = (bf16*)(ws + 140619776);    //   8,388,608
  float* Pacc = (float*)(ws + 149008384);   //  16,777,216  [2][8192][256] fp32
  float* Ml   = (float*)(ws + 165785600);   //     524,288  [8192][4][4]
  // end: 166,309,888
  bf16*  Hbh  = Qh;                         // alias Qh+Ql (disjoint in time)
  bf16*  Hbl  = Kh;                         // alias Kh+Kl

  prep_weights<<<dim3(5130, 12), 256, 0, stream>>>(Wq, bq, Wk, bk, Wv, bv, Wm, bm,
                                                   W1, b1, gm, bt, W2, b2, Wbf, bias);
  transpose_in<<<dim3(64, 8, 4), dim3(32, 8), 0, stream>>>(desc0, desc1, Dm, Hin, XMl);

  for (int l = 0; l < NL; l++) {
    const bf16* wl = Wbf + (size_t)l * 1310720;
    const float* bl = bias + l * 2304;
    int cross = l & 1;
    // fused QKV (Q pre-scaled by log2e/8)
    gemm3<0, 128><<<dim3(64, 6), 256, 0, stream>>>(Hin, 512, XMl, 512,
        wl, wl + 196608, 256, bl, nullptr,
        Qh, Ql, Kh, Kl, Vth, Vtl, nullptr);
    // split-KV attention + combine
    attn3s<<<dim3(16, 16, 2), 512, 0, stream>>>(Qh, Ql, Kh, Kl, Vth, Vtl,
                                                Pacc, Ml, cross);
    attn_combine<<<2048, 256, 0, stream>>>(Pacc, Ml, Oh, Ol);
    // merge: msg = O·Wm^T
    gemm3<2, 64><<<dim3(64, 4), 256, 0, stream>>>(Oh, 256, Ol, 256,
        wl + 393216, wl + 458752, 256, bl + 768, nullptr,
        Hin, XMl, nullptr, nullptr, nullptr, nullptr, nullptr);
    // MLP1 + BN + ReLU
    gemm3<3, 128><<<dim3(64, 4), 256, 0, stream>>>(Hin, 512, XMl, 512,
        wl + 524288, wl + 786432, 512, bl + 1024, bl + 1536,
        Hbh, Hbl, nullptr, nullptr, nullptr, nullptr, nullptr);
    // MLP2 + residual
    gemm3<4, 64><<<dim3(64, 4), 256, 0, stream>>>(Hbh, 512, Hbl, 512,
        wl + 1048576, wl + 1179648, 512, bl + 2048, nullptr,
        Hin, XMl, nullptr, nullptr, nullptr, nullptr, Dm);
  }
  transpose_out<<<dim3(64, 8, 4), dim3(32, 8), 0, stream>>>(Dm, out);
}

// Round 8
// 1885.356 us; speedup vs baseline: 1.2878x; 1.0200x over previous
//
#include <hip/hip_runtime.h>

typedef unsigned short bf16;
typedef __attribute__((ext_vector_type(8))) short bf16x8;
typedef __attribute__((ext_vector_type(4))) float f32x4;
typedef unsigned short u16x4 __attribute__((ext_vector_type(4)));

#define DEVFN static __device__ __forceinline__

#define NL 12

// counted vmcnt wait + raw barrier + compiler fence (T4 pattern, rule #18)
#define VMW(N) asm volatile("s_waitcnt vmcnt(" #N ")" ::: "memory")
#define RBAR() asm volatile("s_barrier" ::: "memory")
#define SCHB() __builtin_amdgcn_sched_barrier(0)

DEVFN unsigned short f2bf(float f) {
  union { float f; unsigned u; } v; v.f = f;
  unsigned u = v.u;
  unsigned r = (u + 0x7fffu + ((u >> 16) & 1u)) >> 16;  // RNE
  return (unsigned short)r;
}
DEVFN float bf2f(unsigned short h) {
  union { unsigned u; float f; } v; v.u = ((unsigned)h) << 16; return v.f;
}
// truncation hi/lo split: 4 ALU ops, pair error ~2^-18
DEVFN void tsplit(float v, unsigned short& h, unsigned short& l) {
  union { float f; unsigned u; } a; a.f = v;
  h = (unsigned short)(a.u >> 16);
  union { float f; unsigned u; } b; b.u = a.u & 0xffff0000u;
  union { float f; unsigned u; } c; c.f = v - b.f;
  l = (unsigned short)(c.u >> 16);
}
// async global->LDS, 16B per lane; dest = wave-uniform base + lane*16
DEVFN void gll16(const bf16* g, bf16* l) {
  __builtin_amdgcn_global_load_lds(
      (const __attribute__((address_space(1))) unsigned int*)g,
      (__attribute__((address_space(3))) unsigned int*)l, 16, 0, 0);
}

#define MFMA_BF16(a, b, c) __builtin_amdgcn_mfma_f32_16x16x32_bf16((a), (b), (c), 0, 0, 0)

// ---------------------------------------------------------------------------
// Weight prep: hi/lo bf16 split of every weight (RNE, one-time). Wq/bq folded
// with Cs = log2(e)/8. Layout per layer (1310720 bf16):
//   [0,196608) Wqkv hi | [196608,393216) Wqkv lo | [393216,458752) Wm hi
//   [458752,524288) Wm lo | [524288,786432) W1 hi | [786432,1048576) W1 lo
//   [1048576,1179648) W2 hi | [1179648,1310720) W2 lo
// f32 bias block (2304): bqkv[768] | bm[256] | geff[512] | beff[512] | b2[256]
// ---------------------------------------------------------------------------
__global__ void prep_weights(const float* __restrict__ Wq, const float* __restrict__ bq,
                             const float* __restrict__ Wk, const float* __restrict__ bk,
                             const float* __restrict__ Wv, const float* __restrict__ bv,
                             const float* __restrict__ Wm, const float* __restrict__ bm,
                             const float* __restrict__ W1, const float* __restrict__ b1,
                             const float* __restrict__ gm, const float* __restrict__ bt,
                             const float* __restrict__ W2, const float* __restrict__ b2,
                             bf16* __restrict__ Wbf, float* __restrict__ bias)
{
  int l = blockIdx.y;
  bf16* wl = Wbf + (size_t)l * 1310720;
  float* bl = bias + l * 2304;
  int idx = blockIdx.x * blockDim.x + threadIdx.x;
  if (idx >= 1310720 + 2304) return;
  const float INV = 1.0f / sqrtf(1.0f + 1e-5f);
  const float Cs = 0.18033688011112042f;  // log2(e)/8

  float w = 0.f;
  int lo = 0;
  if (idx < 393216) {                         // Wqkv
    int j = idx; lo = (j >= 196608); j -= lo * 196608;
    int t = j >> 16;
    int p = (j >> 8) & 255;
    int k = j & 255;
    int c = ((p & 63) << 2) | (p >> 6);       // p = h*64+i -> c = i*4+h
    const float* W = (t == 0) ? Wq : (t == 1) ? Wk : Wv;
    w = W[(size_t)l * 65536 + c * 256 + k];
    if (t == 0) w *= Cs;
  } else if (idx < 524288) {                  // Wm (cols permuted)
    int j = idx - 393216; lo = (j >= 65536); j -= lo * 65536;
    int o = j >> 8, p = j & 255;
    int c = ((p & 63) << 2) | (p >> 6);
    w = Wm[(size_t)l * 65536 + o * 256 + c];
  } else if (idx < 1048576) {                 // W1
    int j = idx - 524288; lo = (j >= 262144); j &= 262143;
    w = W1[(size_t)l * 262144 + j];
  } else if (idx < 1310720) {                 // W2
    int j = idx - 1048576; lo = (j >= 131072); j &= 131071;
    w = W2[(size_t)l * 131072 + j];
  } else {
    int j = idx - 1310720;
    if (j < 768) {
      int t = j >> 8, p = j & 255;
      int c = ((p & 63) << 2) | (p >> 6);
      const float* bsrc = (t == 0) ? bq : (t == 1) ? bk : bv;
      bl[j] = bsrc[l * 256 + c] * ((t == 0) ? Cs : 1.0f);
    } else if (j < 1024) {
      bl[j] = bm[l * 256 + (j - 768)];
    } else if (j < 1536) {
      bl[j] = gm[l * 512 + (j - 1024)] * INV;
    } else if (j < 2048) {
      int o = j - 1536;
      bl[j] = gm[l * 512 + o] * INV * b1[l * 512 + o] + bt[l * 512 + o];
    } else {
      bl[j] = b2[l * 256 + (j - 2048)];
    }
    return;
  }
  unsigned short hi = f2bf(w);
  wl[idx] = lo ? f2bf(w - bf2f(hi)) : hi;
}

// ---------------------------------------------------------------------------
// Input transpose: desc [b,d,n] fp32 -> Dm [xi,256] fp32; Hin[:,0:256]=x hi;
// XMl[:,0:256]=x lo (both lda 512).
// ---------------------------------------------------------------------------
__global__ void transpose_in(const float* __restrict__ s0, const float* __restrict__ s1,
                             float* __restrict__ Dm, bf16* __restrict__ Hin,
                             bf16* __restrict__ XMl)
{
  __shared__ float t[32][33];
  int db = blockIdx.z;
  int dsc = db >> 1, bi = db & 1;
  const float* src = dsc ? s1 : s0;
  int n0 = blockIdx.x * 32, d0 = blockIdx.y * 32;
  int tx = threadIdx.x, ty = threadIdx.y;
  #pragma unroll
  for (int i = 0; i < 32; i += 8)
    t[ty + i][tx] = src[(size_t)(bi * 256 + d0 + ty + i) * 2048 + n0 + tx];
  __syncthreads();
  #pragma unroll
  for (int i = 0; i < 32; i += 8) {
    size_t xi = (size_t)db * 2048 + n0 + ty + i;
    float v = t[tx][ty + i];
    Dm[xi * 256 + d0 + tx] = v;
    unsigned short hi, lo;
    tsplit(v, hi, lo);
    Hin[xi * 512 + d0 + tx] = hi;
    XMl[xi * 512 + d0 + tx] = lo;
  }
}

__global__ void transpose_out(const float* __restrict__ Dm, float* __restrict__ out)
{
  __shared__ float t[32][33];
  int db = blockIdx.z;
  int n0 = blockIdx.x * 32, d0 = blockIdx.y * 32;
  int tx = threadIdx.x, ty = threadIdx.y;
  #pragma unroll
  for (int i = 0; i < 32; i += 8)
    t[ty + i][tx] = Dm[((size_t)db * 2048 + n0 + ty + i) * 256 + d0 + tx];
  __syncthreads();
  #pragma unroll
  for (int i = 0; i < 32; i += 8)
    out[(size_t)(db * 256 + d0 + ty + i) * 2048 + n0 + tx] = t[tx][ty + i];
}

// ---------------------------------------------------------------------------
// 3-term split GEMM, double-buffered global_load_lds staging with counted
// vmcnt + raw barriers (loads for step k+1 fly under step k's MFMAs).
// Tile 128xNT, BK=32, 4 waves (2x2). gsw-swizzle via pre-swizzled source.
// ---------------------------------------------------------------------------
DEVFN int gsw(int row, int col) { return row * 32 + (col ^ ((row & 3) << 3)); }

template<int EPI, int NT>
__global__ __launch_bounds__(256, (NT == 128) ? 2 : 3) void gemm3(
    const bf16* __restrict__ Ah, int lda,
    const bf16* __restrict__ Al, int ldal,
    const bf16* __restrict__ Wh, const bf16* __restrict__ Wl, int K,
    const float* __restrict__ b0, const float* __restrict__ b1,
    bf16* __restrict__ o0, bf16* __restrict__ o1,
    bf16* __restrict__ o2, bf16* __restrict__ o3,
    bf16* __restrict__ o4, bf16* __restrict__ o5,
    float* __restrict__ of)
{
  constexpr int NFR = NT / 32;
  __shared__ bf16 AsH[2][128 * 32];
  __shared__ bf16 AsL[2][128 * 32];
  __shared__ bf16 BsH[2][NT * 32];
  __shared__ bf16 BsL[2][NT * 32];
  int tid = threadIdx.x, lane = tid & 63, wid = tid >> 6;
  int wr = wid >> 1, wc = wid & 1;
  int m0 = blockIdx.x * 128, n0 = blockIdx.y * NT;

  // staging source (pre-swizzled): lane -> row wid*16 + (lane>>2), granule (lane&3)^(row&3)
  int lrow = lane >> 2;
  int g4 = ((lane & 3) ^ (lrow & 3)) << 3;
  const bf16* A0h = Ah + (size_t)(m0 + wid * 16 + lrow) * lda + g4;
  const bf16* A0l = Al + (size_t)(m0 + wid * 16 + lrow) * ldal + g4;
  const bf16* B0h = Wh + (size_t)(n0 + wid * 16 + lrow) * K + g4;
  const bf16* B0l = Wl + (size_t)(n0 + wid * 16 + lrow) * K + g4;
  size_t a64h = (size_t)64 * lda, a64l = (size_t)64 * ldal, b64 = (size_t)64 * K;

  auto issue = [&](int k0, int b) {
    gll16(A0h + k0, &AsH[b][wid * 512]);
    gll16(A0h + a64h + k0, &AsH[b][wid * 512 + 2048]);
    gll16(A0l + k0, &AsL[b][wid * 512]);
    gll16(A0l + a64l + k0, &AsL[b][wid * 512 + 2048]);
    gll16(B0h + k0, &BsH[b][wid * 512]);
    gll16(B0l + k0, &BsL[b][wid * 512]);
    if constexpr (NT == 128) {
      gll16(B0h + b64 + k0, &BsH[b][wid * 512 + 2048]);
      gll16(B0l + b64 + k0, &BsL[b][wid * 512 + 2048]);
    }
  };

  f32x4 zero = {0.f, 0.f, 0.f, 0.f};
  f32x4 acc[4][NFR];
  #pragma unroll
  for (int i = 0; i < 4; i++)
    #pragma unroll
    for (int j = 0; j < NFR; j++) acc[i][j] = zero;

  int fr = lane & 15, kof = (lane >> 4) << 3;
  int cbw = wc * (NT / 2);
  int nk = K >> 5;

  issue(0, 0);
  for (int ks = 0; ks < nk; ks++) {
    int cur = ks & 1;
    if (ks + 1 < nk) {
      issue((ks + 1) << 5, cur ^ 1);
      if constexpr (NT == 128) VMW(8); else VMW(6);  // wait tile ks only
    } else {
      VMW(0);
    }
    RBAR(); SCHB();
    bf16x8 afh[4], afl[4], bfh[NFR], bfl[NFR];
    #pragma unroll
    for (int i = 0; i < 4; i++) {
      afh[i] = *(const bf16x8*)(&AsH[cur][gsw(wr * 64 + i * 16 + fr, kof)]);
      afl[i] = *(const bf16x8*)(&AsL[cur][gsw(wr * 64 + i * 16 + fr, kof)]);
    }
    #pragma unroll
    for (int i = 0; i < NFR; i++) {
      bfh[i] = *(const bf16x8*)(&BsH[cur][gsw(cbw + i * 16 + fr, kof)]);
      bfl[i] = *(const bf16x8*)(&BsL[cur][gsw(cbw + i * 16 + fr, kof)]);
    }
    #pragma unroll
    for (int mi = 0; mi < 4; mi++)
      #pragma unroll
      for (int ni = 0; ni < NFR; ni++) {
        acc[mi][ni] = MFMA_BF16(afh[mi], bfh[ni], acc[mi][ni]);
        acc[mi][ni] = MFMA_BF16(afl[mi], bfh[ni], acc[mi][ni]);
        acc[mi][ni] = MFMA_BF16(afh[mi], bfl[ni], acc[mi][ni]);
      }
    RBAR();  // all waves done reading buf 'cur' before iter ks+1 re-issues it
  }

  #pragma unroll
  for (int mi = 0; mi < 4; mi++) {
    #pragma unroll
    for (int ni = 0; ni < NFR; ni++) {
      int mrow = m0 + wr * 64 + mi * 16 + ((lane >> 4) << 2);
      int ocol = n0 + cbw + ni * 16 + fr;
      if constexpr (EPI == 0) {          // fused QKV
        float bb = b0[ocol];
        if (ocol < 512) {                // Q or K hi/lo [xi,256]
          bf16* Dh = (ocol < 256) ? o0 : o2;
          bf16* Dl = (ocol < 256) ? o1 : o3;
          int oo = ocol & 255;
          #pragma unroll
          for (int r = 0; r < 4; r++) {
            unsigned short hi, lo;
            tsplit(acc[mi][ni][r] + bb, hi, lo);
            Dh[(size_t)(mrow + r) * 256 + oo] = hi;
            Dl[(size_t)(mrow + r) * 256 + oo] = lo;
          }
        } else {                         // V transposed hi/lo
          int c = ocol - 512;
          int dbi = mrow >> 11, nn = mrow & 2047;
          u16x4 ph, pl;
          #pragma unroll
          for (int r = 0; r < 4; r++) {
            unsigned short hi, lo;
            tsplit(acc[mi][ni][r] + bb, hi, lo);
            ph[r] = hi; pl[r] = lo;
          }
          *(u16x4*)(&o4[((size_t)dbi * 256 + c) * 2048 + nn]) = ph;
          *(u16x4*)(&o5[((size_t)dbi * 256 + c) * 2048 + nn]) = pl;
        }
      } else if constexpr (EPI == 2) {   // merge -> msg hi+lo
        float bb = b0[ocol];
        #pragma unroll
        for (int r = 0; r < 4; r++) {
          unsigned short hi, lo;
          tsplit(acc[mi][ni][r] + bb, hi, lo);
          o0[(size_t)(mrow + r) * 512 + 256 + ocol] = hi;
          o1[(size_t)(mrow + r) * 512 + 256 + ocol] = lo;
        }
      } else if constexpr (EPI == 3) {   // BN+ReLU hi+lo
        float ge = b0[ocol], be = b1[ocol];
        #pragma unroll
        for (int r = 0; r < 4; r++) {
          unsigned short hi, lo;
          tsplit(fmaxf(ge * acc[mi][ni][r] + be, 0.f), hi, lo);
          o0[(size_t)(mrow + r) * 512 + ocol] = hi;
          o1[(size_t)(mrow + r) * 512 + ocol] = lo;
        }
      } else {                           // EPI 4: residual
        float bb = b0[ocol];
        #pragma unroll
        for (int r = 0; r < 4; r++) {
          size_t ix = (size_t)(mrow + r) * 256 + ocol;
          float d = of[ix] + acc[mi][ni][r] + bb;
          of[ix] = d;
          unsigned short hi, lo;
          tsplit(d, hi, lo);
          o0[(size_t)(mrow + r) * 512 + ocol] = hi;
          o1[(size_t)(mrow + r) * 512 + ocol] = lo;
        }
      }
    }
  }
}

// ---------------------------------------------------------------------------
// Flash attention, split-KV (2 halves), 3-term QK^T and PV, 3-phase pipelined:
//   vmcnt(2)+bar -> QK^T+softmax(defer-max) -> vmcnt(0)+bar -> issue K(t+1)
//   -> P->LDS + PV -> bar -> issue V(t+1)
// K-load hides under PV; V-load hides under next QK^T+softmax. No drains.
// ---------------------------------------------------------------------------
DEVFN int swz(int row, int col) { return row * 64 + (col ^ ((row & 7) << 3)); }

__global__ __launch_bounds__(512, 4) void attn3s(
    const bf16* __restrict__ Qh, const bf16* __restrict__ Ql,
    const bf16* __restrict__ Kh, const bf16* __restrict__ Kl,
    const bf16* __restrict__ Vth, const bf16* __restrict__ Vtl,
    float* __restrict__ Pacc, float* __restrict__ Ml, int cross)
{
  __shared__ bf16 Ksh[64 * 64];
  __shared__ bf16 Ksl[64 * 64];
  __shared__ bf16 Vsh[64 * 64];
  __shared__ bf16 Vsl[64 * 64];
  __shared__ bf16 Psh[8][1024];
  __shared__ bf16 Psl[8][1024];
  int tid = threadIdx.x, lane = tid & 63, w = tid >> 6;
  int inst = blockIdx.y;
  int half = blockIdx.z;
  int db = inst >> 2, hd = inst & 3;
  int dsc = db >> 1, bi = db & 1;
  int sdb = (cross ? (1 - dsc) : dsc) * 2 + bi;
  size_t xq = (size_t)db * 2048;
  size_t xs = (size_t)sdb * 2048 + half * 1024;
  int n0 = blockIdx.x * 128;

  int fr = lane & 15, kof = (lane >> 4) << 3;

  // Q fragments hi/lo: direct global -> registers
  bf16x8 aqh[2], aql[2];
  #pragma unroll
  for (int kf = 0; kf < 2; kf++) {
    size_t g = (xq + n0 + w * 16 + fr) * 256 + hd * 64 + kf * 32 + kof;
    aqh[kf] = *(const bf16x8*)(Qh + g);
    aql[kf] = *(const bf16x8*)(Ql + g);
  }

  f32x4 zero = {0.f, 0.f, 0.f, 0.f};
  f32x4 oacc[4];
  #pragma unroll
  for (int ni = 0; ni < 4; ni++) oacc[ni] = zero;
  float mrun[4], lrun[4];
  #pragma unroll
  for (int r = 0; r < 4; r++) { mrun[r] = -3.0e38f; lrun[r] = 0.f; }

  bf16x8 vone;
  #pragma unroll
  for (int i = 0; i < 8; i++) vone[i] = (short)0x3F80;  // bf16 1.0

  // staging sources (pre-swizzled): lane -> row w*8 + (lane>>3),
  // granule (lane&7) ^ (row&7)
  int lrow = lane >> 3;
  int g8 = ((lane & 7) ^ (lrow & 7)) << 3;
  int krow = w * 8 + lrow;
  const bf16* Ksrc_h = Kh + (xs + krow) * 256 + hd * 64 + g8;
  const bf16* Ksrc_l = Kl + (xs + krow) * 256 + hd * 64 + g8;
  const bf16* Vsrc_h = Vth + ((size_t)sdb * 256 + hd * 64 + krow) * 2048 + half * 1024 + g8;
  const bf16* Vsrc_l = Vtl + ((size_t)sdb * 256 + hd * 64 + krow) * 2048 + half * 1024 + g8;
  bf16* LKh = Ksh + w * 512;
  bf16* LKl = Ksl + w * 512;
  bf16* LVh = Vsh + w * 512;
  bf16* LVl = Vsl + w * 512;

  // prologue: K(0) then V(0) in flight
  gll16(Ksrc_h, LKh);
  gll16(Ksrc_l, LKl);
  gll16(Vsrc_h, LVh);
  gll16(Vsrc_l, LVl);

  for (int t = 0; t < 16; t++) {
    VMW(2);            // K(t) landed (V(t) may still be in flight)
    RBAR(); SCHB();

    // ---- QK^T (3-term) ----
    f32x4 sacc[4];
    #pragma unroll
    for (int ni = 0; ni < 4; ni++) sacc[ni] = zero;
    #pragma unroll
    for (int kf = 0; kf < 2; kf++) {
      #pragma unroll
      for (int ni = 0; ni < 4; ni++) {
        bf16x8 bkh = *(const bf16x8*)(&Ksh[swz(ni * 16 + fr, kf * 32 + kof)]);
        bf16x8 bkl = *(const bf16x8*)(&Ksl[swz(ni * 16 + fr, kf * 32 + kof)]);
        sacc[ni] = MFMA_BF16(aqh[kf], bkh, sacc[ni]);
        sacc[ni] = MFMA_BF16(aql[kf], bkh, sacc[ni]);
        sacc[ni] = MFMA_BF16(aqh[kf], bkl, sacc[ni]);
      }
    }

    // ---- online softmax with defer-max (T13, exp2 units, THR=8) ----
    float tmr[4];
    bool need = false;
    #pragma unroll
    for (int r = 0; r < 4; r++) {
      float tm = fmaxf(fmaxf(sacc[0][r], sacc[1][r]), fmaxf(sacc[2][r], sacc[3][r]));
      tm = fmaxf(tm, __shfl_xor(tm, 1));
      tm = fmaxf(tm, __shfl_xor(tm, 2));
      tm = fmaxf(tm, __shfl_xor(tm, 4));
      tm = fmaxf(tm, __shfl_xor(tm, 8));
      tmr[r] = tm;
      need = need || (tm > mrun[r] + 8.0f);
    }
    if (__ballot(need)) {
      #pragma unroll
      for (int r = 0; r < 4; r++) {
        float mn = fmaxf(mrun[r], tmr[r]);
        float s = exp2f(mrun[r] - mn);
        mrun[r] = mn;
        lrun[r] *= s;
        #pragma unroll
        for (int ni = 0; ni < 4; ni++) oacc[ni][r] *= s;
      }
    }
    #pragma unroll
    for (int r = 0; r < 4; r++)
      #pragma unroll
      for (int ni = 0; ni < 4; ni++)
        sacc[ni][r] = exp2f(sacc[ni][r] - mrun[r]);

    VMW(0);            // V(t) landed (K(t+1) not yet issued)
    RBAR(); SCHB();    // also: all waves finished QK^T -> K LDS free

    if (t + 1 < 16) {  // K(t+1) flies under P-store + PV
      gll16(Ksrc_h + (size_t)(t + 1) * 16384, LKh);
      gll16(Ksrc_l + (size_t)(t + 1) * 16384, LKl);
    }

    // ---- P -> LDS (own wave region) ----
    bf16* Pwh = &Psh[w][0];
    bf16* Pwl = &Psl[w][0];
    #pragma unroll
    for (int ni = 0; ni < 4; ni++) {
      int col = ni * 16 + fr;
      #pragma unroll
      for (int r = 0; r < 4; r++) {
        int row = ((lane >> 4) << 2) + r;
        unsigned short hi, lo;
        tsplit(sacc[ni][r], hi, lo);
        Pwh[swz(row, col)] = hi;
        Pwl[swz(row, col)] = lo;
      }
    }

    // ---- PV (3-term) + row-sum via ones-MFMA ----
    f32x4 racc = zero;
    #pragma unroll
    for (int kf = 0; kf < 2; kf++) {
      bf16x8 pah = *(const bf16x8*)(&Pwh[swz(fr, kf * 32 + kof)]);
      bf16x8 pal = *(const bf16x8*)(&Pwl[swz(fr, kf * 32 + kof)]);
      #pragma unroll
      for (int ni = 0; ni < 4; ni++) {
        bf16x8 bvh = *(const bf16x8*)(&Vsh[swz(ni * 16 + fr, kf * 32 + kof)]);
        bf16x8 bvl = *(const bf16x8*)(&Vsl[swz(ni * 16 + fr, kf * 32 + kof)]);
        oacc[ni] = MFMA_BF16(pah, bvh, oacc[ni]);
        oacc[ni] = MFMA_BF16(pal, bvh, oacc[ni]);
        oacc[ni] = MFMA_BF16(pah, bvl, oacc[ni]);
      }
      racc = MFMA_BF16(pah, vone, racc);
      racc = MFMA_BF16(pal, vone, racc);
    }
    #pragma unroll
    for (int r = 0; r < 4; r++)
      lrun[r] += racc[r];

    RBAR();            // all waves done PV -> V LDS free
    if (t + 1 < 16) {  // V(t+1) flies under next QK^T + softmax
      gll16(Vsrc_h + (t + 1) * 64, LVh);
      gll16(Vsrc_l + (t + 1) * 64, LVl);
    }
  }

  // store unnormalized partial O (fp32) + per-row (m, l)
  float* Pb = Pacc + (size_t)half * 8192 * 256;
  #pragma unroll
  for (int r = 0; r < 4; r++) {
    int nrow = n0 + w * 16 + ((lane >> 4) << 2) + r;
    size_t row = xq + nrow;
    #pragma unroll
    for (int ni = 0; ni < 4; ni++)
      Pb[row * 256 + hd * 64 + ni * 16 + fr] = oacc[ni][r];
    if (fr == 0) {
      float* mp = Ml + ((row * 4 + hd) << 2) + half * 2;
      mp[0] = mrun[r];
      mp[1] = lrun[r];
    }
  }
}

// ---------------------------------------------------------------------------
// Combine the two KV halves: O = (Pa*wa + Pb*wb) / (la*wa + lb*wb), hi/lo out.
// ---------------------------------------------------------------------------
__global__ __launch_bounds__(256) void attn_combine(
    const float* __restrict__ Pacc, const float* __restrict__ Ml,
    bf16* __restrict__ Oh, bf16* __restrict__ Ol)
{
  int tid = threadIdx.x, lane = tid & 63, w = tid >> 6;
  size_t row = (size_t)blockIdx.x * 4 + w;
  int hd = lane >> 4;
  int c0 = lane * 4;
  const float* mp = Ml + ((row * 4 + hd) << 2);
  float ma = mp[0], la = mp[1], mb = mp[2], lb = mp[3];
  float m = fmaxf(ma, mb);
  float wa = exp2f(ma - m), wb = exp2f(mb - m);
  float inv = 1.0f / (la * wa + lb * wb);
  wa *= inv; wb *= inv;
  f32x4 pa = *(const f32x4*)(Pacc + row * 256 + c0);
  f32x4 pb = *(const f32x4*)(Pacc + (size_t)8192 * 256 + row * 256 + c0);
  u16x4 vh, vl;
  #pragma unroll
  for (int r = 0; r < 4; r++) {
    unsigned short hi, lo;
    tsplit(pa[r] * wa + pb[r] * wb, hi, lo);
    vh[r] = hi; vl[r] = lo;
  }
  *(u16x4*)(Oh + row * 256 + c0) = vh;
  *(u16x4*)(Ol + row * 256 + c0) = vl;
}

// ---------------------------------------------------------------------------
extern "C" void kernel_launch(void* const* d_in, const int* in_sizes, int n_in,
                              void* d_out, int out_size, void* d_ws, size_t ws_size,
                              hipStream_t stream)
{
  (void)in_sizes; (void)n_in; (void)out_size; (void)ws_size;
  const float* desc0 = (const float*)d_in[0];
  const float* desc1 = (const float*)d_in[1];
  const float* Wq = (const float*)d_in[2];
  const float* bq = (const float*)d_in[3];
  const float* Wk = (const float*)d_in[4];
  const float* bk = (const float*)d_in[5];
  const float* Wv = (const float*)d_in[6];
  const float* bv = (const float*)d_in[7];
  const float* Wm = (const float*)d_in[8];
  const float* bm = (const float*)d_in[9];
  const float* W1 = (const float*)d_in[10];
  const float* b1 = (const float*)d_in[11];
  const float* gm = (const float*)d_in[12];
  const float* bt = (const float*)d_in[13];
  const float* W2 = (const float*)d_in[14];
  const float* b2 = (const float*)d_in[15];
  float* out = (float*)d_out;

  char* ws = (char*)d_ws;
  bf16*  Wbf  = (bf16*)(ws + 0);            //  31,457,280
  float* bias = (float*)(ws + 31457280);    //     110,592
  float* Dm   = (float*)(ws + 31567872);    //  16,777,216  fp32 master [xi,256]
  bf16*  Hin  = (bf16*)(ws + 48345088);     //  16,777,216  [xi,512] = xh | msg_h
  bf16*  XMl  = (bf16*)(ws + 65122304);     //  16,777,216  [xi,512] = xl | msg_l
  bf16*  Qh   = (bf16*)(ws + 81899520);     //   8,388,608
  bf16*  Ql   = (bf16*)(ws + 90288128);     //   8,388,608
  bf16*  Kh   = (bf16*)(ws + 98676736);     //   8,388,608
  bf16*  Kl   = (bf16*)(ws + 107065344);    //   8,388,608
  bf16*  Vth  = (bf16*)(ws + 115453952);    //   8,388,608  [db,256,2048]
  bf16*  Vtl  = (bf16*)(ws + 123842560);    //   8,388,608
  bf16*  Oh   = (bf16*)(ws + 132231168);    //   8,388,608
  bf16*  Ol   = (bf16*)(ws + 140619776);    //   8,388,608
  float* Pacc = (float*)(ws + 149008384);   //  16,777,216  [2][8192][256] fp32
  float* Ml   = (float*)(ws + 165785600);   //     524,288  [8192][4][4]
  // end: 166,309,888
  bf16*  Hbh  = Qh;                         // alias Qh+Ql (disjoint in time)
  bf16*  Hbl  = Kh;                         // alias Kh+Kl

  prep_weights<<<dim3(5130, 12), 256, 0, stream>>>(Wq, bq, Wk, bk, Wv, bv, Wm, bm,
                                                   W1, b1, gm, bt, W2, b2, Wbf, bias);
  transpose_in<<<dim3(64, 8, 4), dim3(32, 8), 0, stream>>>(desc0, desc1, Dm, Hin, XMl);

  for (int l = 0; l < NL; l++) {
    const bf16* wl = Wbf + (size_t)l * 1310720;
    const float* bl = bias + l * 2304;
    int cross = l & 1;
    // fused QKV (Q pre-scaled by log2e/8)
    gemm3<0, 128><<<dim3(64, 6), 256, 0, stream>>>(Hin, 512, XMl, 512,
        wl, wl + 196608, 256, bl, nullptr,
        Qh, Ql, Kh, Kl, Vth, Vtl, nullptr);
    // split-KV attention + combine
    attn3s<<<dim3(16, 16, 2), 512, 0, stream>>>(Qh, Ql, Kh, Kl, Vth, Vtl,
                                                Pacc, Ml, cross);
    attn_combine<<<2048, 256, 0, stream>>>(Pacc, Ml, Oh, Ol);
    // merge: msg = O·Wm^T
    gemm3<2, 64><<<dim3(64, 4), 256, 0, stream>>>(Oh, 256, Ol, 256,
        wl + 393216, wl + 458752, 256, bl + 768, nullptr,
        Hin, XMl, nullptr, nullptr, nullptr, nullptr, nullptr);
    // MLP1 + BN + ReLU
    gemm3<3, 128><<<dim3(64, 4), 256, 0, stream>>>(Hin, 512, XMl, 512,
        wl + 524288, wl + 786432, 512, bl + 1024, bl + 1536,
        Hbh, Hbl, nullptr, nullptr, nullptr, nullptr, nullptr);
    // MLP2 + residual
    gemm3<4, 64><<<dim3(64, 4), 256, 0, stream>>>(Hbh, 512, Hbl, 512,
        wl + 1048576, wl + 1179648, 512, bl + 2048, nullptr,
        Hin, XMl, nullptr, nullptr, nullptr, nullptr, Dm);
  }
  transpose_out<<<dim3(64, 8, 4), dim3(32, 8), 0, stream>>>(Dm, out);
}